// Round 13
// baseline (2665.086 us; speedup 1.0000x reference)
//
#include <hip/hip_runtime.h>
#include <hip/hip_bf16.h>
#include <cstdint>
#include <cstddef>

#define LAYERS   8
#define HEADS    16
#define EMB      1024
#define FFND     4096
#define VOCAB    32000
#define SEQ      2048
#define NBATCH   2
#define MROWS    (NBATCH*SEQ)   // 4096
#define HDIM     64
#define QKVSTR   3072
#define LN_EPS   1e-5f
#define QSCALE   0.18033688011112042f   // (1/sqrt(64)) * log2(e)

typedef __hip_bfloat16 bf16;
typedef short short8 __attribute__((ext_vector_type(8)));   // 8 x bf16 bits (4 VGPRs)
typedef float f32x4  __attribute__((ext_vector_type(4)));

// ---------------- async global->LDS (16B per lane) ----------------
__device__ __forceinline__ void async_copy16(const bf16* g, bf16* l) {
  __builtin_amdgcn_global_load_lds(
      (const __attribute__((address_space(1))) void*)g,
      (__attribute__((address_space(3))) void*)l, 16, 0, 0);
}

__device__ __forceinline__ uint32_t bfbits(float x) {
  __hip_bfloat16 h = __float2bfloat16(x);
  return (uint32_t)reinterpret_cast<uint16_t&>(h);
}

// ---------------- fp32 -> bf16 bulk convert ----------------
struct __align__(8) B4 { bf16 a, b, c, d; };

__global__ void k_f32_to_bf16(const float* __restrict__ in, bf16* __restrict__ out, long n4) {
  long i = (long)blockIdx.x * blockDim.x + threadIdx.x;
  const long stride = (long)gridDim.x * blockDim.x;
  for (; i < n4; i += stride) {
    float4 v = reinterpret_cast<const float4*>(in)[i];
    B4 o;
    o.a = __float2bfloat16(v.x);
    o.b = __float2bfloat16(v.y);
    o.c = __float2bfloat16(v.z);
    o.d = __float2bfloat16(v.w);
    reinterpret_cast<B4*>(out)[i] = o;
  }
}

// ---------------- embedding: x = tok_emb[idx] + pos_emb ----------------
__global__ void k_embed(const int* __restrict__ idx, const float* __restrict__ tok,
                        const float* __restrict__ pos, float* __restrict__ x) {
  const int row  = blockIdx.x;           // 0..4095 = b*SEQ + t
  const int tpos = row & (SEQ - 1);
  const int token = idx[row];
  const float4* te = (const float4*)(tok + (long)token * EMB);
  const float4* pe = (const float4*)(pos + (long)tpos * EMB);
  float4* xo = (float4*)(x + (long)row * EMB);
  for (int i = threadIdx.x; i < EMB / 4; i += blockDim.x) {
    float4 a = te[i], b = pe[i];
    a.x += b.x; a.y += b.y; a.z += b.z; a.w += b.w;
    xo[i] = a;
  }
}

// ---------------- unified per-layer weight transpose (6 matrices, 1 dispatch) ----------------
__global__ void k_transpose_all(const float* __restrict__ wq, const float* __restrict__ wk,
                                const float* __restrict__ wv, const float* __restrict__ wo,
                                const float* __restrict__ w1, const float* __restrict__ w2,
                                bf16* __restrict__ qkvT, bf16* __restrict__ woT,
                                bf16* __restrict__ w1T, bf16* __restrict__ w2T) {
  __shared__ float tile[32][33];
  const int bid = blockIdx.x;
  const float* in; bf16* out; int K, N, bx, by;
  if (bid < 4096) {
    const int rest = bid & 1023;
    switch (bid >> 10) {
      case 0:  in = wq; out = qkvT;                 break;
      case 1:  in = wk; out = qkvT + EMB * EMB;     break;
      case 2:  in = wv; out = qkvT + 2 * EMB * EMB; break;
      default: in = wo; out = woT;                  break;
    }
    K = EMB; N = EMB; bx = rest & 31; by = rest >> 5;
  } else if (bid < 8192) {
    const int rest = bid - 4096;
    in = w1; out = w1T; K = EMB; N = FFND;
    bx = rest & 127; by = rest >> 7;
  } else {
    const int rest = bid - 8192;
    in = w2; out = w2T; K = FFND; N = EMB;
    bx = rest & 31; by = rest >> 5;
  }
  const int n0 = bx * 32, k0 = by * 32;
  const int tx = threadIdx.x, ty = threadIdx.y;   // (32,8)
  for (int i = 0; i < 32; i += 8)
    tile[ty + i][tx] = in[(long)(k0 + ty + i) * N + n0 + tx];
  __syncthreads();
  for (int i = 0; i < 32; i += 8)
    out[(long)(n0 + ty + i) * K + k0 + tx] = __float2bfloat16(tile[tx][ty + i]);
}

// ---------------- LayerNorm: wave-per-row (4 rows/block), fp32 in -> bf16 out ----------------
__global__ __launch_bounds__(256)
void k_layernorm(const float* __restrict__ x, const float* __restrict__ g,
                 const float* __restrict__ b, bf16* __restrict__ out) {
  const int wid  = threadIdx.x >> 6;
  const int lane = threadIdx.x & 63;
  const long row = (long)blockIdx.x * 4 + wid;
  const float4* xr = (const float4*)(x + row * EMB);
  float4 xv[4];
  float s = 0.f, sq = 0.f;
#pragma unroll
  for (int i = 0; i < 4; i++) {
    xv[i] = xr[lane + i * 64];
    s  += xv[i].x + xv[i].y + xv[i].z + xv[i].w;
    sq += xv[i].x * xv[i].x + xv[i].y * xv[i].y + xv[i].z * xv[i].z + xv[i].w * xv[i].w;
  }
#pragma unroll
  for (int m = 1; m < 64; m <<= 1) { s += __shfl_xor(s, m); sq += __shfl_xor(sq, m); }
  const float mean = s * (1.f / EMB);
  const float var  = sq * (1.f / EMB) - mean * mean;
  const float rstd = rsqrtf(var + LN_EPS);
  const float4* gv = (const float4*)g;
  const float4* bv = (const float4*)b;
  bf16* orow = out + row * EMB;
#pragma unroll
  for (int i = 0; i < 4; i++) {
    const int c4 = lane + i * 64;
    const float4 gg = gv[c4], bb = bv[c4];
    uint2 o;
    o.x = (bfbits((xv[i].y - mean) * rstd * gg.y + bb.y) << 16) |
           bfbits((xv[i].x - mean) * rstd * gg.x + bb.x);
    o.y = (bfbits((xv[i].w - mean) * rstd * gg.w + bb.w) << 16) |
           bfbits((xv[i].z - mean) * rstd * gg.z + bb.z);
    *reinterpret_cast<uint2*>(&orow[c4 * 4]) = o;
  }
}

// ======================================================================
// 256x256 GEMM, 2 super-phases/tile. C[M,N] = A[M,K]*Bt[N,K]^T
// MODE 0 (QKV): Q cols (<EMB) pre-scaled by QSCALE -> outB; K cols -> outB;
//   V cols (>=2*EMB) written TRANSPOSED into vt_out[bh*64+d][t] (round-13 fusion).
// MODE 2: outB = bf16(relu(acc+bias))
// ======================================================================
template<int MODE>
__global__ __launch_bounds__(512, 2)
void gemm256(const bf16* __restrict__ A, const bf16* __restrict__ Bt,
             int M, int N, int K,
             bf16* __restrict__ outB, const float* __restrict__ bias,
             bf16* __restrict__ vt_out) {
  extern __shared__ __align__(16) char smem[];   // 128 KB
  char* const smA = smem;
  char* const smB = smem + 65536;

  const int t    = threadIdx.x;
  const int lane = t & 63;
  const int wid  = t >> 6;
  const int wr   = wid >> 2;          // 0..1 : A half (rows wr*128..)
  const int wc   = wid & 3;           // 0..3 : cols wc*64.. ; B half = wc>>1
  const int lrow = lane & 15;
  const int ks16 = (lane >> 4) * 16;  // k-slice byte offset
  const int rswz = (lrow & 7) << 4;   // read-side XOR

  // linearize + bijective XCD chunk swizzle (nwg % 8 == 0)
  int lin = blockIdx.x * gridDim.y + blockIdx.y;
  { const int nwg = gridDim.x * gridDim.y; const int per = nwg >> 3;
    lin = (lin & 7) * per + (lin >> 3); }
  const int gx8  = gridDim.x * 8;
  const int half = lin / gx8;
  const int rem  = lin - half * gx8;
  const long bm  = (long)(half * 8 + (rem & 7)) * 256;
  const long bn  = (long)(rem >> 3) * 256;
  const int NT = K >> 6;

  const int row0 = wid * 8 + (lane >> 3);               // dest row of load 0
  const int col0 = ((lane & 7) ^ (lane >> 3)) * 8;      // pre-swizzled src col
  const int row1 = row0 + 64;                           // load 1: row+64, same col
  const int dst0 = wid * 1024;
  const int dst1 = 8192 + wid * 1024;
  const bf16* const gA = A + bm * K;
  const bf16* const gB = Bt + bn * K;

  auto STG = [&](char* ring, const bf16* g_, int tile, int h) {
    char* slot = ring + (((tile << 1) + h) & 3) * 16384;
    const bf16* sb = g_ + ((long)h * 128) * K + (long)tile * 64;
    async_copy16(sb + (long)row0 * K + col0, (bf16*)(slot + dst0));
    async_copy16(sb + (long)row1 * K + col0, (bf16*)(slot + dst1));
  };
  auto LDA8 = [&](int u, int m, int kk) -> short8 {
    const int off = (m * 16 + lrow) * 128 + ((kk * 64 + ks16) ^ rswz);
    return *reinterpret_cast<const short8*>(smA + (((u << 1) + wr) & 3) * 16384 + off);
  };
  auto LDB8 = [&](int u, int n, int kk) -> short8 {
    const int off = ((wc & 1) * 64 + n * 16 + lrow) * 128 + ((kk * 64 + ks16) ^ rswz);
    return *reinterpret_cast<const short8*>(smB + (((u << 1) + (wc >> 1)) & 3) * 16384 + off);
  };
#define MF(a_, b_, c_) __builtin_amdgcn_mfma_f32_16x16x32_bf16(a_, b_, c_, 0, 0, 0)

  f32x4 acc[8][4] = {};

  // prologue: B(0) A(0) B(1); last 4 loads (B(1)) may stay in flight
  STG(smB, gB, 0, 0); STG(smB, gB, 0, 1);
  STG(smA, gA, 0, 0); STG(smA, gA, 0, 1);
  STG(smB, gB, 1, 0); STG(smB, gB, 1, 1);
  asm volatile("s_waitcnt vmcnt(4)" ::: "memory");
  __builtin_amdgcn_s_barrier();

  short8 bq[4][2];
  for (int u = 0; u < NT; u++) {
    // ---- super-phase A: read B(all) + A(m0..m3); stage A(u+1) ----
#pragma unroll
    for (int n = 0; n < 4; n++) { bq[n][0] = LDB8(u, n, 0); bq[n][1] = LDB8(u, n, 1); }
    short8 a0 = LDA8(u, 0, 0), a1 = LDA8(u, 0, 1), a2 = LDA8(u, 1, 0), a3 = LDA8(u, 1, 1);
    short8 a4 = LDA8(u, 2, 0), a5 = LDA8(u, 2, 1), a6 = LDA8(u, 3, 0), a7 = LDA8(u, 3, 1);
    if (u + 1 < NT) { STG(smA, gA, u + 1, 0); STG(smA, gA, u + 1, 1); }
    __builtin_amdgcn_s_barrier();
    asm volatile("s_waitcnt lgkmcnt(0)" ::: "memory");
    __builtin_amdgcn_sched_barrier(0);
    __builtin_amdgcn_s_setprio(1);
#pragma unroll
    for (int n = 0; n < 4; n++) {
      acc[0][n] = MF(a0, bq[n][0], acc[0][n]); acc[0][n] = MF(a1, bq[n][1], acc[0][n]);
      acc[1][n] = MF(a2, bq[n][0], acc[1][n]); acc[1][n] = MF(a3, bq[n][1], acc[1][n]);
      acc[2][n] = MF(a4, bq[n][0], acc[2][n]); acc[2][n] = MF(a5, bq[n][1], acc[2][n]);
      acc[3][n] = MF(a6, bq[n][0], acc[3][n]); acc[3][n] = MF(a7, bq[n][1], acc[3][n]);
    }
    __builtin_amdgcn_s_setprio(0);
    __builtin_amdgcn_s_barrier();

    // ---- super-phase B: read A(m4..m7); stage B(u+2); tile-end wait ----
    a0 = LDA8(u, 4, 0); a1 = LDA8(u, 4, 1); a2 = LDA8(u, 5, 0); a3 = LDA8(u, 5, 1);
    a4 = LDA8(u, 6, 0); a5 = LDA8(u, 6, 1); a6 = LDA8(u, 7, 0); a7 = LDA8(u, 7, 1);
    if (u + 2 < NT) { STG(smB, gB, u + 2, 0); STG(smB, gB, u + 2, 1); }
    __builtin_amdgcn_s_barrier();
    asm volatile("s_waitcnt lgkmcnt(0)" ::: "memory");
    __builtin_amdgcn_sched_barrier(0);
    __builtin_amdgcn_s_setprio(1);
#pragma unroll
    for (int n = 0; n < 4; n++) {
      acc[4][n] = MF(a0, bq[n][0], acc[4][n]); acc[4][n] = MF(a1, bq[n][1], acc[4][n]);
      acc[5][n] = MF(a2, bq[n][0], acc[5][n]); acc[5][n] = MF(a3, bq[n][1], acc[5][n]);
      acc[6][n] = MF(a4, bq[n][0], acc[6][n]); acc[6][n] = MF(a5, bq[n][1], acc[6][n]);
      acc[7][n] = MF(a6, bq[n][0], acc[7][n]); acc[7][n] = MF(a7, bq[n][1], acc[7][n]);
    }
    __builtin_amdgcn_s_setprio(0);
    if (u + 2 < NT) { asm volatile("s_waitcnt vmcnt(4)" ::: "memory"); }
    else            { asm volatile("s_waitcnt vmcnt(0)" ::: "memory"); }
    __builtin_amdgcn_s_barrier();
  }

  // epilogue
  const long rb = bm + wr * 128 + (lane >> 4) * 4;
  const long cb = bn + wc * 64 + lrow;
#pragma unroll
  for (int m = 0; m < 8; m++) {
#pragma unroll
    for (int n = 0; n < 4; n++) {
      const long col = cb + n * 16;
      if (MODE == 0 && col >= 2 * EMB) {
        // V slice: write transposed into vt_out[(b*16+h)*64+d][t], 4 consecutive t
        const int  dc = (int)(col - 2 * EMB);
        const long t0 = rb + m * 16;
        const long vr = ((t0 >> 11) * HEADS + (dc >> 6)) * (long)HDIM + (dc & 63);
        uint2 pv;
        pv.x = (bfbits(acc[m][n][1]) << 16) | bfbits(acc[m][n][0]);
        pv.y = (bfbits(acc[m][n][3]) << 16) | bfbits(acc[m][n][2]);
        *reinterpret_cast<uint2*>(&vt_out[vr * SEQ + (t0 & (SEQ - 1))]) = pv;
      } else {
#pragma unroll
        for (int r = 0; r < 4; r++) {
          const long row = rb + m * 16 + r;
          float vv = acc[m][n][r];
          if (MODE == 0) {
            if (col < EMB) vv *= QSCALE;     // pre-scale Q slice for attention
            outB[row * N + col] = __float2bfloat16(vv);
          } else {
            vv += bias[col];
            outB[row * N + col] = __float2bfloat16(vv > 0.f ? vv : 0.f);
          }
        }
      }
    }
  }
#undef MF
}

// ======================================================================
// Logits GEMM: continuous-K ring across 2 N-subtiles (round-13).
// One pipeline of TT=32 tiles (or 16 for the odd tail group); v0 epilogue
// overlaps v1's prefetched tiles. outF = acc (fp32).
// ======================================================================
__global__ __launch_bounds__(512, 2)
void gemm_logits(const bf16* __restrict__ A, const bf16* __restrict__ Bt,
                 int M, int N, int K, float* __restrict__ outF) {
  extern __shared__ __align__(16) char smem[];   // 128 KB
  char* const smA = smem;
  char* const smB = smem + 65536;

  const int t    = threadIdx.x;
  const int lane = t & 63;
  const int wid  = t >> 6;
  const int wr   = wid >> 2;
  const int wc   = wid & 3;
  const int lrow = lane & 15;
  const int ks16 = (lane >> 4) * 16;
  const int rswz = (lrow & 7) << 4;

  int lin = blockIdx.x * gridDim.y + blockIdx.y;
  { const int nwg = gridDim.x * gridDim.y; const int per = nwg >> 3;
    lin = (lin & 7) * per + (lin >> 3); }
  const int gx8  = gridDim.x * 8;
  const int half = lin / gx8;
  const int rem  = lin - half * gx8;
  const long bm  = (long)(half * 8 + (rem & 7)) * 256;
  const long bn0 = (long)(rem >> 3) * 512;
  const long bn1 = bn0 + 256;
  const int NT = K >> 6;                         // 16
  const int TT = (bn1 < N) ? (NT * 2) : NT;      // 32 normally; 16 for tail group

  const int row0 = wid * 8 + (lane >> 3);
  const int col0 = ((lane & 7) ^ (lane >> 3)) * 8;
  const int row1 = row0 + 64;
  const int dst0 = wid * 1024;
  const int dst1 = 8192 + wid * 1024;
  const bf16* const gA  = A + bm * K;
  const bf16* const gB0 = Bt + bn0 * K;
  const bf16* const gB1 = Bt + bn1 * K;

  // slot indexed by continuous tile number; k-source = tile & (NT-1)
  auto STG2 = [&](char* ring, const bf16* src, int slotTile, int h) {
    char* slot = ring + (((slotTile << 1) + h) & 3) * 16384;
    const bf16* sb = src + ((long)h * 128) * K + (long)(slotTile & (NT - 1)) * 64;
    async_copy16(sb + (long)row0 * K + col0, (bf16*)(slot + dst0));
    async_copy16(sb + (long)row1 * K + col0, (bf16*)(slot + dst1));
  };
  auto LDA8 = [&](int u, int m, int kk) -> short8 {
    const int off = (m * 16 + lrow) * 128 + ((kk * 64 + ks16) ^ rswz);
    return *reinterpret_cast<const short8*>(smA + (((u << 1) + wr) & 3) * 16384 + off);
  };
  auto LDB8 = [&](int u, int n, int kk) -> short8 {
    const int off = ((wc & 1) * 64 + n * 16 + lrow) * 128 + ((kk * 64 + ks16) ^ rswz);
    return *reinterpret_cast<const short8*>(smB + (((u << 1) + (wc >> 1)) & 3) * 16384 + off);
  };
#define MF(a_, b_, c_) __builtin_amdgcn_mfma_f32_16x16x32_bf16(a_, b_, c_, 0, 0, 0)

  f32x4 acc[8][4] = {};
  const long rb = bm + wr * 128 + (lane >> 4) * 4;

  auto epi = [&](long bn) {
    const long cb = bn + wc * 64 + lrow;
#pragma unroll
    for (int m = 0; m < 8; m++)
#pragma unroll
      for (int n = 0; n < 4; n++) {
        const long col = cb + n * 16;
#pragma unroll
        for (int r = 0; r < 4; r++)
          outF[(rb + m * 16 + r) * N + col] = acc[m][n][r];
      }
  };

  // prologue: B(0) A(0) B(1)
  STG2(smB, gB0, 0, 0); STG2(smB, gB0, 0, 1);
  STG2(smA, gA,  0, 0); STG2(smA, gA,  0, 1);
  STG2(smB, gB0, 1, 0); STG2(smB, gB0, 1, 1);
  asm volatile("s_waitcnt vmcnt(4)" ::: "memory");
  __builtin_amdgcn_s_barrier();

  short8 bq[4][2];
  for (int u = 0; u < TT; u++) {
    // ---- super-phase A ----
#pragma unroll
    for (int n = 0; n < 4; n++) { bq[n][0] = LDB8(u, n, 0); bq[n][1] = LDB8(u, n, 1); }
    short8 a0 = LDA8(u, 0, 0), a1 = LDA8(u, 0, 1), a2 = LDA8(u, 1, 0), a3 = LDA8(u, 1, 1);
    short8 a4 = LDA8(u, 2, 0), a5 = LDA8(u, 2, 1), a6 = LDA8(u, 3, 0), a7 = LDA8(u, 3, 1);
    if (u + 1 < TT) { STG2(smA, gA, u + 1, 0); STG2(smA, gA, u + 1, 1); }
    __builtin_amdgcn_s_barrier();
    asm volatile("s_waitcnt lgkmcnt(0)" ::: "memory");
    __builtin_amdgcn_sched_barrier(0);
    __builtin_amdgcn_s_setprio(1);
#pragma unroll
    for (int n = 0; n < 4; n++) {
      acc[0][n] = MF(a0, bq[n][0], acc[0][n]); acc[0][n] = MF(a1, bq[n][1], acc[0][n]);
      acc[1][n] = MF(a2, bq[n][0], acc[1][n]); acc[1][n] = MF(a3, bq[n][1], acc[1][n]);
      acc[2][n] = MF(a4, bq[n][0], acc[2][n]); acc[2][n] = MF(a5, bq[n][1], acc[2][n]);
      acc[3][n] = MF(a6, bq[n][0], acc[3][n]); acc[3][n] = MF(a7, bq[n][1], acc[3][n]);
    }
    __builtin_amdgcn_s_setprio(0);
    __builtin_amdgcn_s_barrier();

    // ---- super-phase B ----
    a0 = LDA8(u, 4, 0); a1 = LDA8(u, 4, 1); a2 = LDA8(u, 5, 0); a3 = LDA8(u, 5, 1);
    a4 = LDA8(u, 6, 0); a5 = LDA8(u, 6, 1); a6 = LDA8(u, 7, 0); a7 = LDA8(u, 7, 1);
    if (u + 2 < TT) {
      const bf16* bs = ((u + 2) >= NT) ? gB1 : gB0;
      STG2(smB, bs, u + 2, 0); STG2(smB, bs, u + 2, 1);
    }
    __builtin_amdgcn_s_barrier();
    asm volatile("s_waitcnt lgkmcnt(0)" ::: "memory");
    __builtin_amdgcn_sched_barrier(0);
    __builtin_amdgcn_s_setprio(1);
#pragma unroll
    for (int n = 0; n < 4; n++) {
      acc[4][n] = MF(a0, bq[n][0], acc[4][n]); acc[4][n] = MF(a1, bq[n][1], acc[4][n]);
      acc[5][n] = MF(a2, bq[n][0], acc[5][n]); acc[5][n] = MF(a3, bq[n][1], acc[5][n]);
      acc[6][n] = MF(a4, bq[n][0], acc[6][n]); acc[6][n] = MF(a5, bq[n][1], acc[6][n]);
      acc[7][n] = MF(a6, bq[n][0], acc[7][n]); acc[7][n] = MF(a7, bq[n][1], acc[7][n]);
    }
    __builtin_amdgcn_s_setprio(0);
    // Ledger: vmcnt(4) leaves only the newest 4 loads (B(u+2)) in flight;
    // at u==TT-2 nothing was staged -> drain to 0 (tail rule).
    if (u + 2 < TT) { asm volatile("s_waitcnt vmcnt(4)" ::: "memory"); }
    else            { asm volatile("s_waitcnt vmcnt(0)" ::: "memory"); }
    __builtin_amdgcn_s_barrier();

    if (u == NT - 1 && TT > NT) {
      epi(bn0);                       // v0 epilogue overlaps v1's in-flight prefetch
#pragma unroll
      for (int m = 0; m < 8; m++)
#pragma unroll
        for (int n = 0; n < 4; n++)
#pragma unroll
          for (int r = 0; r < 4; r++) acc[m][n][r] = 0.f;
    }
  }
  epi(TT > NT ? bn1 : bn0);
#undef MF
}

// ---------------- 128x128 GEMM, split-K=2 + 2-phase dbuf ----------------
#define BM 128
#define BN 128
#define BK 32

__global__ __launch_bounds__(256)
void gemm_bt(const bf16* __restrict__ A, const bf16* __restrict__ Bt,
             int M, int N, int K,
             float* __restrict__ outF, const float* __restrict__ bias) {
  __shared__ __align__(16) bf16 lA[2][BM * BK];
  __shared__ __align__(16) bf16 lB[2][BN * BK];
  const int t    = threadIdx.x;
  const int lane = t & 63;
  const int wid  = t >> 6;
  const int wr   = wid >> 1;
  const int wc   = wid & 1;
  const long bm  = (long)blockIdx.y * BM;
  const long bn  = (long)blockIdx.x * BN;
  const int  kz  = blockIdx.z;
  const int  Kh  = K >> 1;

  f32x4 acc[4][4] = {};

  const long arow = t >> 2;                               // 0..63
  const int  acol = (((t & 3) ^ ((t >> 2) & 3)) * 8);     // pre-swizzled src col
  const bf16* gA = A  + (bm + arow) * K + kz * Kh + acol;
  const bf16* gB = Bt + (bn + arow) * K + kz * Kh + acol;
  const long astep = 64L * K;

  auto STGBT = [&](int buf, int k0) {
    async_copy16(gA + k0,         &lA[buf][wid * 512]);
    async_copy16(gA + k0 + astep, &lA[buf][wid * 512 + 2048]);
    async_copy16(gB + k0,         &lB[buf][wid * 512]);
    async_copy16(gB + k0 + astep, &lB[buf][wid * 512 + 2048]);
  };

  STGBT(0, 0);
  __syncthreads();

  int cur = 0;
  for (int k0 = 0; k0 < Kh; k0 += BK) {
    if (k0 + BK < Kh) STGBT(cur ^ 1, k0 + BK);   // overlaps with compute below

    const int ksel = (((lane >> 4) ^ (lane & 3)) * 8);    // swizzled read col
    short8 af[4], bfv[4];
#pragma unroll
    for (int i = 0; i < 4; i++) {
      af[i]  = *reinterpret_cast<const short8*>(&lA[cur][(wr * 64 + i * 16 + (lane & 15)) * BK + ksel]);
      bfv[i] = *reinterpret_cast<const short8*>(&lB[cur][(wc * 64 + i * 16 + (lane & 15)) * BK + ksel]);
    }
#pragma unroll
    for (int i = 0; i < 4; i++)
#pragma unroll
      for (int j = 0; j < 4; j++)
        acc[i][j] = __builtin_amdgcn_mfma_f32_16x16x32_bf16(af[i], bfv[j], acc[i][j], 0, 0, 0);
    __syncthreads();   // drains next-tile stage; protects cur buffer reuse
    cur ^= 1;
  }

  const long rbase = bm + wr * 64 + (lane >> 4) * 4;
  const long cbase = bn + wc * 64 + (lane & 15);
#pragma unroll
  for (int i = 0; i < 4; i++) {
#pragma unroll
    for (int j = 0; j < 4; j++) {
      const long col = cbase + j * 16;
      const float bv = kz ? 0.f : bias[col];
#pragma unroll
      for (int r = 0; r < 4; r++) {
        const long row = rbase + i * 16 + r;
        unsafeAtomicAdd(&outF[row * N + col], acc[i][j][r] + bv);
      }
    }
  }
}

// ---------------- flash attention (causal), 2 q-frags/wave, defer-max, paired balance ----------------
__global__ __launch_bounds__(256)
void k_attn(const bf16* __restrict__ qkv, const bf16* __restrict__ vt, bf16* __restrict__ o) {
  const int bh = blockIdx.y;
  const int qt = (bh & 16) ? blockIdx.x : (gridDim.x - 1 - blockIdx.x);
  const int b  = bh >> 4;
  const int h  = bh & 15;
  const int t0b = qt * 128;
  const int tid = threadIdx.x;
  const int w    = tid >> 6;
  const int lane = tid & 63;
  const int lg = lane >> 4;            // 0..3
  const int li = lane & 15;
  const int t0w = t0b + w * 32;        // frag f rows: t0w + f*16 + li

  __shared__ __align__(16) bf16 Kl[2][64 * 64];
  __shared__ __align__(16) bf16 Vl[2][64 * 64];
  __shared__ __align__(16) bf16 Pl[4][32 * 64];   // per-wave P[q][k], swizzled

  const bf16* qbase = qkv + (long)(b * SEQ) * QKVSTR + h * HDIM;   // Q pre-scaled by QSCALE
  const bf16* kbase = qkv + (long)(b * SEQ) * QKVSTR + EMB + h * HDIM;
  const bf16* vbase = vt + (long)bh * HDIM * SEQ;

  short8 qf[2][2];
#pragma unroll
  for (int f = 0; f < 2; f++) {
    const bf16* qrow = qbase + (long)(t0w + f * 16 + li) * QKVSTR;
    qf[f][0] = *reinterpret_cast<const short8*>(&qrow[lg * 8]);
    qf[f][1] = *reinterpret_cast<const short8*>(&qrow[32 + lg * 8]);
  }

  f32x4 oacc[2][4] = {};
  float mrow[2] = {-1e30f, -1e30f}, lrow[2] = {0.f, 0.f};

  const int nkt = (t0b >> 6) + 1;            // last k-tile index (diag spans 2 tiles)
  const int l8  = lane >> 3;                 // 0..7
  const int sl8 = ((lane & 7) ^ l8) * 8;     // pre-swizzled source slot (rule 21)

  char* const Pw = (char*)&Pl[w][0];
  const int pswz = (li & 7) << 4;

  // prologue: stage tile 0 into buffer 0
#pragma unroll
  for (int sh = 0; sh < 2; sh++) {
    const int r = sh * 32 + w * 8 + l8;
    async_copy16(kbase + (long)r * QKVSTR + sl8, &Kl[0][(sh * 32 + w * 8) * 64]);
    async_copy16(vbase + (long)r * SEQ + sl8,    &Vl[0][(sh * 32 + w * 8) * 64]);
  }
  __syncthreads();

  int cur = 0;
  for (int kt = 0; kt <= nkt; kt++) {
    const int s0 = kt * 64;
    if (kt < nkt) {                          // stage next tile
      const int s0n = s0 + 64;
      bf16* Kn = &Kl[cur ^ 1][0];
      bf16* Vn = &Vl[cur ^ 1][0];
#pragma unroll
      for (int sh = 0; sh < 2; sh++) {
        const int r = sh * 32 + w * 8 + l8;
        async_copy16(kbase + (long)(s0n + r) * QKVSTR + sl8, Kn + (sh * 32 + w * 8) * 64);
        async_copy16(vbase + (long)r * SEQ + s0n + sl8,      Vn + (sh * 32 + w * 8) * 64);
      }
    }

    // S^T = mfma(K, Q) — Q already carries QSCALE (exp2 domain)
    f32x4 s[2][4] = {};
#pragma unroll
    for (int kk = 0; kk < 2; kk++)
#pragma unroll
      for (int sf = 0; sf < 4; sf++) {
        const short8 kf = *reinterpret_cast<const short8*>(
            &Kl[cur][(sf * 16 + li) * 64 + ((((kk << 2) | lg) ^ (li & 7)) * 8)]);
        s[0][sf] = __builtin_amdgcn_mfma_f32_16x16x32_bf16(kf, qf[0][kk], s[0][sf], 0, 0, 0);
        s[1][sf] = __builtin_amdgcn_mfma_f32_16x16x32_bf16(kf, qf[1][kk], s[1][sf], 0, 0, 0);
      }

    const bool diag = (kt >= nkt - 1);       // tiles < nkt-1 provably unmasked
    if (diag) {
#pragma unroll
      for (int f = 0; f < 2; f++)
#pragma unroll
        for (int sf = 0; sf < 4; sf++)
#pragma unroll
          for (int r = 0; r < 4; r++)
            if (s0 + sf * 16 + lg * 4 + r > t0w + f * 16 + li) s[f][sf][r] = -1e30f;
    }

    // per-lane softmax per frag, defer-max (T13, THR=8 in exp2 domain)
#pragma unroll
    for (int f = 0; f < 2; f++) {
      float mx = -1e30f;
#pragma unroll
      for (int sf = 0; sf < 4; sf++)
        mx = fmaxf(mx, fmaxf(fmaxf(s[f][sf][0], s[f][sf][1]), fmaxf(s[f][sf][2], s[f][sf][3])));
      mx = fmaxf(mx, __shfl_xor(mx, 16));
      mx = fmaxf(mx, __shfl_xor(mx, 32));
      if (__any(mx > mrow[f] + 8.f)) {       // rescale only when max grew materially
        const float mnew = fmaxf(mrow[f], mx);
        const float alpha = exp2f(mrow[f] - mnew);
        mrow[f] = mnew;
        lrow[f] *= alpha;
#pragma unroll
        for (int d = 0; d < 4; d++)
#pragma unroll
          for (int r = 0; r < 4; r++) oacc[f][d][r] *= alpha;
      }
      float rs = 0.f;
#pragma unroll
      for (int sf = 0; sf < 4; sf++)
#pragma unroll
        for (int r = 0; r < 4; r++) {
          const float pv = exp2f(s[f][sf][r] - mrow[f]);   // bounded by 2^8
          s[f][sf][r] = pv;
          rs += pv;
        }
      rs += __shfl_xor(rs, 16);
      rs += __shfl_xor(rs, 32);
      lrow[f] += rs;

      // P write: row f*16+li, 4 contiguous k per sf, 16B-granule swizzle
#pragma unroll
      for (int sf = 0; sf < 4; sf++) {
        uint2 pw2;
        pw2.x = (bfbits(s[f][sf][1]) << 16) | bfbits(s[f][sf][0]);
        pw2.y = (bfbits(s[f][sf][3]) << 16) | bfbits(s[f][sf][2]);
        *reinterpret_cast<uint2*>(Pw + (f * 16 + li) * 128 + ((sf * 32 + lg * 8) ^ pswz)) = pw2;
      }
    }

    // O^T += mfma(V, P^T); vf shared across frags
#pragma unroll
    for (int kk = 0; kk < 2; kk++) {
      const short8 pb0 = *reinterpret_cast<const short8*>(
          Pw + li * 128 + ((kk * 64 + lg * 16) ^ pswz));
      const short8 pb1 = *reinterpret_cast<const short8*>(
          Pw + (16 + li) * 128 + ((kk * 64 + lg * 16) ^ pswz));
#pragma unroll
      for (int d = 0; d < 4; d++) {
        const short8 vf = *reinterpret_cast<const short8*>(
            &Vl[cur][(d * 16 + li) * 64 + ((((kk << 2) | lg) ^ (li & 7)) * 8)]);
        oacc[0][d] = __builtin_amdgcn_mfma_f32_16x16x32_bf16(vf, pb0, oacc[0][d], 0, 0, 0);
        oacc[1][d] = __builtin_amdgcn_mfma_f32_16x16x32_bf16(vf, pb1, oacc[1][d], 0, 0, 0);
      }
    }

    __syncthreads();   // drains stage vmcnt + protects buf reuse
    cur ^= 1;
  }

  // epilogue: lane owns rows q = t0w + f*16 + li
#pragma unroll
  for (int f = 0; f < 2; f++) {
    const float inv = 1.f / lrow[f];
    bf16* orow = o + (long)(b * SEQ + t0w + f * 16 + li) * EMB + h * HDIM;
#pragma unroll
    for (int d = 0; d < 4; d++) {
      uint2 ow;
      ow.x = (bfbits(oacc[f][d][1] * inv) << 16) | bfbits(oacc[f][d][0] * inv);
      ow.y = (bfbits(oacc[f][d][3] * inv) << 16) | bfbits(oacc[f][d][2] * inv);
      *reinterpret_cast<uint2*>(&orow[d * 16 + lg * 4]) = ow;
    }
  }
}

// ---------------- host launcher ----------------
extern "C" void kernel_launch(void* const* d_in, const int* in_sizes, int n_in,
                              void* d_out, int out_size, void* d_ws, size_t ws_size,
                              hipStream_t stream) {
  (void)in_sizes; (void)n_in; (void)out_size; (void)ws_size;
  const int*   idx = (const int*)  d_in[0];
  const float* tok = (const float*)d_in[1];
  const float* pos = (const float*)d_in[2];
  const float* wq  = (const float*)d_in[3];
  const float* wk  = (const float*)d_in[4];
  const float* wv  = (const float*)d_in[5];
  const float* wo  = (const float*)d_in[6];
  const float* bo  = (const float*)d_in[7];
  const float* w1  = (const float*)d_in[8];
  const float* b1  = (const float*)d_in[9];
  const float* w2  = (const float*)d_in[10];
  const float* b2  = (const float*)d_in[11];
  const float* g1  = (const float*)d_in[12];
  const float* be1 = (const float*)d_in[13];
  const float* g2  = (const float*)d_in[14];
  const float* be2 = (const float*)d_in[15];
  const float* gf  = (const float*)d_in[16];
  const float* bef = (const float*)d_in[17];
  float* out = (float*)d_out;

  // allow 128 KB dynamic LDS (idempotent, host-side, capture-safe)
  (void)hipFuncSetAttribute((const void*)gemm256<0>, hipFuncAttributeMaxDynamicSharedMemorySize, 131072);
  (void)hipFuncSetAttribute((const void*)gemm256<2>, hipFuncAttributeMaxDynamicSharedMemorySize, 131072);
  (void)hipFuncSetAttribute((const void*)gemm_logits, hipFuncAttributeMaxDynamicSharedMemorySize, 131072);

  char* p = (char*)d_ws;
  auto take = [&p](size_t bytes) { char* r = p; p += (bytes + 255) & ~(size_t)255; return r; };
  float* xf   = (float*)take((size_t)MROWS * EMB * 4);
  bf16*  hb   = (bf16*) take((size_t)MROWS * EMB * 2);
  bf16*  qkvb = (bf16*) take((size_t)MROWS * QKVSTR * 2);
  bf16*  vtb  = (bf16*) take((size_t)MROWS * EMB * 2);
  bf16*  ab   = (bf16*) take((size_t)MROWS * EMB * 2);
  bf16*  fb   = (bf16*) take((size_t)MROWS * FFND * 2);
  bf16*  wqkvT= (bf16*) take((size_t)QKVSTR * EMB * 2);
  bf16*  woT  = (bf16*) take((size_t)EMB * EMB * 2);
  bf16*  w1T  = (bf16*) take((size_t)FFND * EMB * 2);
  bf16*  w2T  = (bf16*) take((size_t)EMB * FFND * 2);
  bf16*  tokT = (bf16*) take((size_t)VOCAB * EMB * 2);

  k_f32_to_bf16<<<2048, 256, 0, stream>>>(tok, tokT, (long)VOCAB * EMB / 4);
  k_embed<<<MROWS, 256, 0, stream>>>(idx, tok, pos, xf);

  const dim3 tb(32, 8);

  for (int l = 0; l < LAYERS; l++) {
    const size_t we = (size_t)l * EMB * EMB;
    const size_t wfo = (size_t)l * EMB * FFND;
    k_transpose_all<<<12288, tb, 0, stream>>>(
        wq + we, wk + we, wv + we, wo + we, w1 + wfo, w2 + wfo, wqkvT, woT, w1T, w2T);

    k_layernorm<<<MROWS / 4, 256, 0, stream>>>(xf, g1 + l * EMB, be1 + l * EMB, hb);
    gemm256<0><<<dim3(QKVSTR / 256, MROWS / 256), 512, 131072, stream>>>(
        hb, wqkvT, MROWS, QKVSTR, EMB, qkvb, nullptr, vtb);
    k_attn<<<dim3(SEQ / 128, NBATCH * HEADS), 256, 0, stream>>>(qkvb, vtb, ab);
    gemm_bt<<<dim3(EMB / BN, MROWS / BM, 2), 256, 0, stream>>>(ab, woT, MROWS, EMB, EMB, xf, bo + l * EMB);
    k_layernorm<<<MROWS / 4, 256, 0, stream>>>(xf, g2 + l * EMB, be2 + l * EMB, hb);
    gemm256<2><<<dim3(FFND / 256, MROWS / 256), 512, 131072, stream>>>(
        hb, w1T, MROWS, FFND, EMB, fb, b1 + l * FFND, nullptr);
    gemm_bt<<<dim3(EMB / BN, MROWS / BM, 2), 256, 0, stream>>>(fb, w2T, MROWS, EMB, FFND, xf, b2 + l * EMB);
  }

  k_layernorm<<<MROWS / 4, 256, 0, stream>>>(xf, gf, bef, hb);
  // logits: 63 bn-groups x 2 subtiles, continuous-K ring; 63*16=1008 blocks (%8==0)
  gemm_logits<<<dim3(63, MROWS / 256), 512, 131072, stream>>>(
      hb, tokT, MROWS, VOCAB, EMB, out);
}

// Round 14
// 2643.970 us; speedup vs baseline: 1.0080x; 1.0080x over previous
//
#include <hip/hip_runtime.h>
#include <hip/hip_bf16.h>
#include <cstdint>
#include <cstddef>

#define LAYERS   8
#define HEADS    16
#define EMB      1024
#define FFND     4096
#define VOCAB    32000
#define SEQ      2048
#define NBATCH   2
#define MROWS    (NBATCH*SEQ)   // 4096
#define HDIM     64
#define QKVSTR   3072
#define LN_EPS   1e-5f
#define QSCALE   0.18033688011112042f   // (1/sqrt(64)) * log2(e)

// transposed-weight pack layout (elements)
#define WT_QKV   0
#define WT_WO    3145728
#define WT_W1    4194304
#define WT_W2    8388608
#define WT_LAYER 12582912

typedef __hip_bfloat16 bf16;
typedef short short8 __attribute__((ext_vector_type(8)));   // 8 x bf16 bits (4 VGPRs)
typedef float f32x4  __attribute__((ext_vector_type(4)));

// ---------------- async global->LDS (16B per lane) ----------------
__device__ __forceinline__ void async_copy16(const bf16* g, bf16* l) {
  __builtin_amdgcn_global_load_lds(
      (const __attribute__((address_space(1))) void*)g,
      (__attribute__((address_space(3))) void*)l, 16, 0, 0);
}

__device__ __forceinline__ uint32_t bfbits(float x) {
  __hip_bfloat16 h = __float2bfloat16(x);
  return (uint32_t)reinterpret_cast<uint16_t&>(h);
}

// ---------------- fp32 -> bf16 bulk convert ----------------
struct __align__(8) B4 { bf16 a, b, c, d; };

__global__ void k_f32_to_bf16(const float* __restrict__ in, bf16* __restrict__ out, long n4) {
  long i = (long)blockIdx.x * blockDim.x + threadIdx.x;
  const long stride = (long)gridDim.x * blockDim.x;
  for (; i < n4; i += stride) {
    float4 v = reinterpret_cast<const float4*>(in)[i];
    B4 o;
    o.a = __float2bfloat16(v.x);
    o.b = __float2bfloat16(v.y);
    o.c = __float2bfloat16(v.z);
    o.d = __float2bfloat16(v.w);
    reinterpret_cast<B4*>(out)[i] = o;
  }
}

// ---------------- embedding: x = tok_emb[idx] + pos_emb ----------------
__global__ void k_embed(const int* __restrict__ idx, const float* __restrict__ tok,
                        const float* __restrict__ pos, float* __restrict__ x) {
  const int row  = blockIdx.x;           // 0..4095 = b*SEQ + t
  const int tpos = row & (SEQ - 1);
  const int token = idx[row];
  const float4* te = (const float4*)(tok + (long)token * EMB);
  const float4* pe = (const float4*)(pos + (long)tpos * EMB);
  float4* xo = (float4*)(x + (long)row * EMB);
  for (int i = threadIdx.x; i < EMB / 4; i += blockDim.x) {
    float4 a = te[i], b = pe[i];
    a.x += b.x; a.y += b.y; a.z += b.z; a.w += b.w;
    xo[i] = a;
  }
}

// ---------------- weight transpose: fp32 [K][N] -> bf16 [N][K], multi-layer ----------------
// 12288 blocks per layer; blockIdx.x spans layers*12288 (prepass) or 12288
// (per-layer fallback, layer derived = 0, caller passes layer-offset pointers).
__global__ void k_transpose_wall(const float* __restrict__ wq, const float* __restrict__ wk,
                                 const float* __restrict__ wv, const float* __restrict__ wo,
                                 const float* __restrict__ w1, const float* __restrict__ w2,
                                 bf16* __restrict__ wT) {
  __shared__ float tile[32][33];
  int bid = blockIdx.x;
  const int layer = bid / 12288;
  bid -= layer * 12288;
  const long weOff = (long)layer * EMB * EMB;
  const long wfOff = (long)layer * EMB * FFND;
  bf16* const base = wT + (long)layer * WT_LAYER;
  const float* in; bf16* out; int K, N, bx, by;
  if (bid < 4096) {
    const int rest = bid & 1023;
    switch (bid >> 10) {
      case 0:  in = wq + weOff; out = base + WT_QKV;               break;
      case 1:  in = wk + weOff; out = base + WT_QKV + EMB * EMB;   break;
      case 2:  in = wv + weOff; out = base + WT_QKV + 2 * EMB * EMB; break;
      default: in = wo + weOff; out = base + WT_WO;                break;
    }
    K = EMB; N = EMB; bx = rest & 31; by = rest >> 5;
  } else if (bid < 8192) {
    const int rest = bid - 4096;
    in = w1 + wfOff; out = base + WT_W1; K = EMB; N = FFND;
    bx = rest & 127; by = rest >> 7;
  } else {
    const int rest = bid - 8192;
    in = w2 + wfOff; out = base + WT_W2; K = FFND; N = EMB;
    bx = rest & 31; by = rest >> 5;
  }
  const int n0 = bx * 32, k0 = by * 32;
  const int tx = threadIdx.x, ty = threadIdx.y;   // (32,8)
  for (int i = 0; i < 32; i += 8)
    tile[ty + i][tx] = in[(long)(k0 + ty + i) * N + n0 + tx];
  __syncthreads();
  for (int i = 0; i < 32; i += 8)
    out[(long)(n0 + ty + i) * K + k0 + tx] = __float2bfloat16(tile[tx][ty + i]);
}

// ---------------- LayerNorm: wave-per-row (4 rows/block), fp32 in -> bf16 out ----------------
__global__ __launch_bounds__(256)
void k_layernorm(const float* __restrict__ x, const float* __restrict__ g,
                 const float* __restrict__ b, bf16* __restrict__ out) {
  const int wid  = threadIdx.x >> 6;
  const int lane = threadIdx.x & 63;
  const long row = (long)blockIdx.x * 4 + wid;
  const float4* xr = (const float4*)(x + row * EMB);
  float4 xv[4];
  float s = 0.f, sq = 0.f;
#pragma unroll
  for (int i = 0; i < 4; i++) {
    xv[i] = xr[lane + i * 64];
    s  += xv[i].x + xv[i].y + xv[i].z + xv[i].w;
    sq += xv[i].x * xv[i].x + xv[i].y * xv[i].y + xv[i].z * xv[i].z + xv[i].w * xv[i].w;
  }
#pragma unroll
  for (int m = 1; m < 64; m <<= 1) { s += __shfl_xor(s, m); sq += __shfl_xor(sq, m); }
  const float mean = s * (1.f / EMB);
  const float var  = sq * (1.f / EMB) - mean * mean;
  const float rstd = rsqrtf(var + LN_EPS);
  const float4* gv = (const float4*)g;
  const float4* bv = (const float4*)b;
  bf16* orow = out + row * EMB;
#pragma unroll
  for (int i = 0; i < 4; i++) {
    const int c4 = lane + i * 64;
    const float4 gg = gv[c4], bb = bv[c4];
    uint2 o;
    o.x = (bfbits((xv[i].y - mean) * rstd * gg.y + bb.y) << 16) |
           bfbits((xv[i].x - mean) * rstd * gg.x + bb.x);
    o.y = (bfbits((xv[i].w - mean) * rstd * gg.w + bb.w) << 16) |
           bfbits((xv[i].z - mean) * rstd * gg.z + bb.z);
    *reinterpret_cast<uint2*>(&orow[c4 * 4]) = o;
  }
}

// ======================================================================
// 256x256 GEMM, 2 super-phases/tile. C[M,N] = A[M,K]*Bt[N,K]^T
// MODE 0 (QKV): Q cols (<EMB) pre-scaled by QSCALE -> outB; K cols -> outB;
//   V cols (>=2*EMB) written TRANSPOSED into vt_out[bh*64+d][t].
// MODE 2: outB = bf16(relu(acc+bias)); MODE 3: outF = acc (fp32, single
// epilogue at kernel end -- stores must never interleave the vmcnt ring).
// ======================================================================
template<int MODE>
__global__ __launch_bounds__(512, 2)
void gemm256(const bf16* __restrict__ A, const bf16* __restrict__ Bt,
             int M, int N, int K,
             bf16* __restrict__ outB, const float* __restrict__ bias,
             bf16* __restrict__ vt_out, float* __restrict__ outF) {
  extern __shared__ __align__(16) char smem[];   // 128 KB
  char* const smA = smem;
  char* const smB = smem + 65536;

  const int t    = threadIdx.x;
  const int lane = t & 63;
  const int wid  = t >> 6;
  const int wr   = wid >> 2;          // 0..1 : A half (rows wr*128..)
  const int wc   = wid & 3;           // 0..3 : cols wc*64.. ; B half = wc>>1
  const int lrow = lane & 15;
  const int ks16 = (lane >> 4) * 16;  // k-slice byte offset
  const int rswz = (lrow & 7) << 4;   // read-side XOR

  // linearize + bijective XCD chunk swizzle (nwg % 8 == 0)
  int lin = blockIdx.x * gridDim.y + blockIdx.y;
  { const int nwg = gridDim.x * gridDim.y; const int per = nwg >> 3;
    lin = (lin & 7) * per + (lin >> 3); }
  const int gx8  = gridDim.x * 8;
  const int half = lin / gx8;
  const int rem  = lin - half * gx8;
  const long bm  = (long)(half * 8 + (rem & 7)) * 256;
  const long bn  = (long)(rem >> 3) * 256;
  const int NT = K >> 6;

  const int row0 = wid * 8 + (lane >> 3);               // dest row of load 0
  const int col0 = ((lane & 7) ^ (lane >> 3)) * 8;      // pre-swizzled src col
  const int row1 = row0 + 64;                           // load 1: row+64, same col
  const int dst0 = wid * 1024;
  const int dst1 = 8192 + wid * 1024;
  const bf16* const gA = A + bm * K;
  const bf16* const gB = Bt + bn * K;

  auto STG = [&](char* ring, const bf16* g_, int tile, int h) {
    char* slot = ring + (((tile << 1) + h) & 3) * 16384;
    const bf16* sb = g_ + ((long)h * 128) * K + (long)tile * 64;
    async_copy16(sb + (long)row0 * K + col0, (bf16*)(slot + dst0));
    async_copy16(sb + (long)row1 * K + col0, (bf16*)(slot + dst1));
  };
  auto LDA8 = [&](int u, int m, int kk) -> short8 {
    const int off = (m * 16 + lrow) * 128 + ((kk * 64 + ks16) ^ rswz);
    return *reinterpret_cast<const short8*>(smA + (((u << 1) + wr) & 3) * 16384 + off);
  };
  auto LDB8 = [&](int u, int n, int kk) -> short8 {
    const int off = ((wc & 1) * 64 + n * 16 + lrow) * 128 + ((kk * 64 + ks16) ^ rswz);
    return *reinterpret_cast<const short8*>(smB + (((u << 1) + (wc >> 1)) & 3) * 16384 + off);
  };
#define MF(a_, b_, c_) __builtin_amdgcn_mfma_f32_16x16x32_bf16(a_, b_, c_, 0, 0, 0)

  f32x4 acc[8][4] = {};

  // prologue: B(0) A(0) B(1); last 4 loads (B(1)) may stay in flight
  STG(smB, gB, 0, 0); STG(smB, gB, 0, 1);
  STG(smA, gA, 0, 0); STG(smA, gA, 0, 1);
  STG(smB, gB, 1, 0); STG(smB, gB, 1, 1);
  asm volatile("s_waitcnt vmcnt(4)" ::: "memory");
  __builtin_amdgcn_s_barrier();

  short8 bq[4][2];
  for (int u = 0; u < NT; u++) {
    // ---- super-phase A: read B(all) + A(m0..m3); stage A(u+1) ----
#pragma unroll
    for (int n = 0; n < 4; n++) { bq[n][0] = LDB8(u, n, 0); bq[n][1] = LDB8(u, n, 1); }
    short8 a0 = LDA8(u, 0, 0), a1 = LDA8(u, 0, 1), a2 = LDA8(u, 1, 0), a3 = LDA8(u, 1, 1);
    short8 a4 = LDA8(u, 2, 0), a5 = LDA8(u, 2, 1), a6 = LDA8(u, 3, 0), a7 = LDA8(u, 3, 1);
    if (u + 1 < NT) { STG(smA, gA, u + 1, 0); STG(smA, gA, u + 1, 1); }
    __builtin_amdgcn_s_barrier();
    asm volatile("s_waitcnt lgkmcnt(0)" ::: "memory");
    __builtin_amdgcn_sched_barrier(0);
    __builtin_amdgcn_s_setprio(1);
#pragma unroll
    for (int n = 0; n < 4; n++) {
      acc[0][n] = MF(a0, bq[n][0], acc[0][n]); acc[0][n] = MF(a1, bq[n][1], acc[0][n]);
      acc[1][n] = MF(a2, bq[n][0], acc[1][n]); acc[1][n] = MF(a3, bq[n][1], acc[1][n]);
      acc[2][n] = MF(a4, bq[n][0], acc[2][n]); acc[2][n] = MF(a5, bq[n][1], acc[2][n]);
      acc[3][n] = MF(a6, bq[n][0], acc[3][n]); acc[3][n] = MF(a7, bq[n][1], acc[3][n]);
    }
    __builtin_amdgcn_s_setprio(0);
    __builtin_amdgcn_s_barrier();

    // ---- super-phase B: read A(m4..m7); stage B(u+2); tile-end wait ----
    a0 = LDA8(u, 4, 0); a1 = LDA8(u, 4, 1); a2 = LDA8(u, 5, 0); a3 = LDA8(u, 5, 1);
    a4 = LDA8(u, 6, 0); a5 = LDA8(u, 6, 1); a6 = LDA8(u, 7, 0); a7 = LDA8(u, 7, 1);
    if (u + 2 < NT) { STG(smB, gB, u + 2, 0); STG(smB, gB, u + 2, 1); }
    __builtin_amdgcn_s_barrier();
    asm volatile("s_waitcnt lgkmcnt(0)" ::: "memory");
    __builtin_amdgcn_sched_barrier(0);
    __builtin_amdgcn_s_setprio(1);
#pragma unroll
    for (int n = 0; n < 4; n++) {
      acc[4][n] = MF(a0, bq[n][0], acc[4][n]); acc[4][n] = MF(a1, bq[n][1], acc[4][n]);
      acc[5][n] = MF(a2, bq[n][0], acc[5][n]); acc[5][n] = MF(a3, bq[n][1], acc[5][n]);
      acc[6][n] = MF(a4, bq[n][0], acc[6][n]); acc[6][n] = MF(a5, bq[n][1], acc[6][n]);
      acc[7][n] = MF(a6, bq[n][0], acc[7][n]); acc[7][n] = MF(a7, bq[n][1], acc[7][n]);
    }
    __builtin_amdgcn_s_setprio(0);
    if (u + 2 < NT) { asm volatile("s_waitcnt vmcnt(4)" ::: "memory"); }
    else            { asm volatile("s_waitcnt vmcnt(0)" ::: "memory"); }
    __builtin_amdgcn_s_barrier();
  }

  // epilogue (single, at kernel end)
  const long rb = bm + wr * 128 + (lane >> 4) * 4;
  const long cb = bn + wc * 64 + lrow;
#pragma unroll
  for (int m = 0; m < 8; m++) {
#pragma unroll
    for (int n = 0; n < 4; n++) {
      const long col = cb + n * 16;
      if (MODE == 0 && col >= 2 * EMB) {
        // V slice: write transposed into vt_out[(b*16+h)*64+d][t], 4 consecutive t
        const int  dc = (int)(col - 2 * EMB);
        const long t0 = rb + m * 16;
        const long vr = ((t0 >> 11) * HEADS + (dc >> 6)) * (long)HDIM + (dc & 63);
        uint2 pv;
        pv.x = (bfbits(acc[m][n][1]) << 16) | bfbits(acc[m][n][0]);
        pv.y = (bfbits(acc[m][n][3]) << 16) | bfbits(acc[m][n][2]);
        *reinterpret_cast<uint2*>(&vt_out[vr * SEQ + (t0 & (SEQ - 1))]) = pv;
      } else {
#pragma unroll
        for (int r = 0; r < 4; r++) {
          const long row = rb + m * 16 + r;
          float vv = acc[m][n][r];
          if (MODE == 0) {
            if (col < EMB) vv *= QSCALE;     // pre-scale Q slice for attention
            outB[row * N + col] = __float2bfloat16(vv);
          } else if (MODE == 2) {
            vv += bias[col];
            outB[row * N + col] = __float2bfloat16(vv > 0.f ? vv : 0.f);
          } else {
            outF[row * N + col] = vv;
          }
        }
      }
    }
  }
#undef MF
}

// ---------------- 128x128 GEMM, split-K=2 + 2-phase dbuf ----------------
#define BM 128
#define BN 128
#define BK 32

__global__ __launch_bounds__(256)
void gemm_bt(const bf16* __restrict__ A, const bf16* __restrict__ Bt,
             int M, int N, int K,
             float* __restrict__ outF, const float* __restrict__ bias) {
  __shared__ __align__(16) bf16 lA[2][BM * BK];
  __shared__ __align__(16) bf16 lB[2][BN * BK];
  const int t    = threadIdx.x;
  const int lane = t & 63;
  const int wid  = t >> 6;
  const int wr   = wid >> 1;
  const int wc   = wid & 1;
  const long bm  = (long)blockIdx.y * BM;
  const long bn  = (long)blockIdx.x * BN;
  const int  kz  = blockIdx.z;
  const int  Kh  = K >> 1;

  f32x4 acc[4][4] = {};

  const long arow = t >> 2;                               // 0..63
  const int  acol = (((t & 3) ^ ((t >> 2) & 3)) * 8);     // pre-swizzled src col
  const bf16* gA = A  + (bm + arow) * K + kz * Kh + acol;
  const bf16* gB = Bt + (bn + arow) * K + kz * Kh + acol;
  const long astep = 64L * K;

  auto STGBT = [&](int buf, int k0) {
    async_copy16(gA + k0,         &lA[buf][wid * 512]);
    async_copy16(gA + k0 + astep, &lA[buf][wid * 512 + 2048]);
    async_copy16(gB + k0,         &lB[buf][wid * 512]);
    async_copy16(gB + k0 + astep, &lB[buf][wid * 512 + 2048]);
  };

  STGBT(0, 0);
  __syncthreads();

  int cur = 0;
  for (int k0 = 0; k0 < Kh; k0 += BK) {
    if (k0 + BK < Kh) STGBT(cur ^ 1, k0 + BK);   // overlaps with compute below

    const int ksel = (((lane >> 4) ^ (lane & 3)) * 8);    // swizzled read col
    short8 af[4], bfv[4];
#pragma unroll
    for (int i = 0; i < 4; i++) {
      af[i]  = *reinterpret_cast<const short8*>(&lA[cur][(wr * 64 + i * 16 + (lane & 15)) * BK + ksel]);
      bfv[i] = *reinterpret_cast<const short8*>(&lB[cur][(wc * 64 + i * 16 + (lane & 15)) * BK + ksel]);
    }
#pragma unroll
    for (int i = 0; i < 4; i++)
#pragma unroll
      for (int j = 0; j < 4; j++)
        acc[i][j] = __builtin_amdgcn_mfma_f32_16x16x32_bf16(af[i], bfv[j], acc[i][j], 0, 0, 0);
    __syncthreads();   // drains next-tile stage; protects cur buffer reuse
    cur ^= 1;
  }

  const long rbase = bm + wr * 64 + (lane >> 4) * 4;
  const long cbase = bn + wc * 64 + (lane & 15);
#pragma unroll
  for (int i = 0; i < 4; i++) {
#pragma unroll
    for (int j = 0; j < 4; j++) {
      const long col = cbase + j * 16;
      const float bv = kz ? 0.f : bias[col];
#pragma unroll
      for (int r = 0; r < 4; r++) {
        const long row = rbase + i * 16 + r;
        unsafeAtomicAdd(&outF[row * N + col], acc[i][j][r] + bv);
      }
    }
  }
}

// ---------------- flash attention (causal), 2 q-frags/wave, defer-max, paired balance ----------------
__global__ __launch_bounds__(256)
void k_attn(const bf16* __restrict__ qkv, const bf16* __restrict__ vt, bf16* __restrict__ o) {
  const int bh = blockIdx.y;
  const int qt = (bh & 16) ? blockIdx.x : (gridDim.x - 1 - blockIdx.x);
  const int b  = bh >> 4;
  const int h  = bh & 15;
  const int t0b = qt * 128;
  const int tid = threadIdx.x;
  const int w    = tid >> 6;
  const int lane = tid & 63;
  const int lg = lane >> 4;            // 0..3
  const int li = lane & 15;
  const int t0w = t0b + w * 32;        // frag f rows: t0w + f*16 + li

  __shared__ __align__(16) bf16 Kl[2][64 * 64];
  __shared__ __align__(16) bf16 Vl[2][64 * 64];
  __shared__ __align__(16) bf16 Pl[4][32 * 64];   // per-wave P[q][k], swizzled

  const bf16* qbase = qkv + (long)(b * SEQ) * QKVSTR + h * HDIM;   // Q pre-scaled by QSCALE
  const bf16* kbase = qkv + (long)(b * SEQ) * QKVSTR + EMB + h * HDIM;
  const bf16* vbase = vt + (long)bh * HDIM * SEQ;

  short8 qf[2][2];
#pragma unroll
  for (int f = 0; f < 2; f++) {
    const bf16* qrow = qbase + (long)(t0w + f * 16 + li) * QKVSTR;
    qf[f][0] = *reinterpret_cast<const short8*>(&qrow[lg * 8]);
    qf[f][1] = *reinterpret_cast<const short8*>(&qrow[32 + lg * 8]);
  }

  f32x4 oacc[2][4] = {};
  float mrow[2] = {-1e30f, -1e30f}, lrow[2] = {0.f, 0.f};

  const int nkt = (t0b >> 6) + 1;            // last k-tile index (diag spans 2 tiles)
  const int l8  = lane >> 3;                 // 0..7
  const int sl8 = ((lane & 7) ^ l8) * 8;     // pre-swizzled source slot (rule 21)

  char* const Pw = (char*)&Pl[w][0];
  const int pswz = (li & 7) << 4;

  // prologue: stage tile 0 into buffer 0
#pragma unroll
  for (int sh = 0; sh < 2; sh++) {
    const int r = sh * 32 + w * 8 + l8;
    async_copy16(kbase + (long)r * QKVSTR + sl8, &Kl[0][(sh * 32 + w * 8) * 64]);
    async_copy16(vbase + (long)r * SEQ + sl8,    &Vl[0][(sh * 32 + w * 8) * 64]);
  }
  __syncthreads();

  int cur = 0;
  for (int kt = 0; kt <= nkt; kt++) {
    const int s0 = kt * 64;
    if (kt < nkt) {                          // stage next tile
      const int s0n = s0 + 64;
      bf16* Kn = &Kl[cur ^ 1][0];
      bf16* Vn = &Vl[cur ^ 1][0];
#pragma unroll
      for (int sh = 0; sh < 2; sh++) {
        const int r = sh * 32 + w * 8 + l8;
        async_copy16(kbase + (long)(s0n + r) * QKVSTR + sl8, Kn + (sh * 32 + w * 8) * 64);
        async_copy16(vbase + (long)r * SEQ + s0n + sl8,      Vn + (sh * 32 + w * 8) * 64);
      }
    }

    // S^T = mfma(K, Q) — Q already carries QSCALE (exp2 domain)
    f32x4 s[2][4] = {};
#pragma unroll
    for (int kk = 0; kk < 2; kk++)
#pragma unroll
      for (int sf = 0; sf < 4; sf++) {
        const short8 kf = *reinterpret_cast<const short8*>(
            &Kl[cur][(sf * 16 + li) * 64 + ((((kk << 2) | lg) ^ (li & 7)) * 8)]);
        s[0][sf] = __builtin_amdgcn_mfma_f32_16x16x32_bf16(kf, qf[0][kk], s[0][sf], 0, 0, 0);
        s[1][sf] = __builtin_amdgcn_mfma_f32_16x16x32_bf16(kf, qf[1][kk], s[1][sf], 0, 0, 0);
      }

    const bool diag = (kt >= nkt - 1);       // tiles < nkt-1 provably unmasked
    if (diag) {
#pragma unroll
      for (int f = 0; f < 2; f++)
#pragma unroll
        for (int sf = 0; sf < 4; sf++)
#pragma unroll
          for (int r = 0; r < 4; r++)
            if (s0 + sf * 16 + lg * 4 + r > t0w + f * 16 + li) s[f][sf][r] = -1e30f;
    }

    // per-lane softmax per frag, defer-max (T13, THR=8 in exp2 domain)
#pragma unroll
    for (int f = 0; f < 2; f++) {
      float mx = -1e30f;
#pragma unroll
      for (int sf = 0; sf < 4; sf++)
        mx = fmaxf(mx, fmaxf(fmaxf(s[f][sf][0], s[f][sf][1]), fmaxf(s[f][sf][2], s[f][sf][3])));
      mx = fmaxf(mx, __shfl_xor(mx, 16));
      mx = fmaxf(mx, __shfl_xor(mx, 32));
      if (__any(mx > mrow[f] + 8.f)) {       // rescale only when max grew materially
        const float mnew = fmaxf(mrow[f], mx);
        const float alpha = exp2f(mrow[f] - mnew);
        mrow[f] = mnew;
        lrow[f] *= alpha;
#pragma unroll
        for (int d = 0; d < 4; d++)
#pragma unroll
          for (int r = 0; r < 4; r++) oacc[f][d][r] *= alpha;
      }
      float rs = 0.f;
#pragma unroll
      for (int sf = 0; sf < 4; sf++)
#pragma unroll
        for (int r = 0; r < 4; r++) {
          const float pv = exp2f(s[f][sf][r] - mrow[f]);   // bounded by 2^8
          s[f][sf][r] = pv;
          rs += pv;
        }
      rs += __shfl_xor(rs, 16);
      rs += __shfl_xor(rs, 32);
      lrow[f] += rs;

      // P write: row f*16+li, 4 contiguous k per sf, 16B-granule swizzle
#pragma unroll
      for (int sf = 0; sf < 4; sf++) {
        uint2 pw2;
        pw2.x = (bfbits(s[f][sf][1]) << 16) | bfbits(s[f][sf][0]);
        pw2.y = (bfbits(s[f][sf][3]) << 16) | bfbits(s[f][sf][2]);
        *reinterpret_cast<uint2*>(Pw + (f * 16 + li) * 128 + ((sf * 32 + lg * 8) ^ pswz)) = pw2;
      }
    }

    // O^T += mfma(V, P^T); vf shared across frags
#pragma unroll
    for (int kk = 0; kk < 2; kk++) {
      const short8 pb0 = *reinterpret_cast<const short8*>(
          Pw + li * 128 + ((kk * 64 + lg * 16) ^ pswz));
      const short8 pb1 = *reinterpret_cast<const short8*>(
          Pw + (16 + li) * 128 + ((kk * 64 + lg * 16) ^ pswz));
#pragma unroll
      for (int d = 0; d < 4; d++) {
        const short8 vf = *reinterpret_cast<const short8*>(
            &Vl[cur][(d * 16 + li) * 64 + ((((kk << 2) | lg) ^ (li & 7)) * 8)]);
        oacc[0][d] = __builtin_amdgcn_mfma_f32_16x16x32_bf16(vf, pb0, oacc[0][d], 0, 0, 0);
        oacc[1][d] = __builtin_amdgcn_mfma_f32_16x16x32_bf16(vf, pb1, oacc[1][d], 0, 0, 0);
      }
    }

    if (kt < nkt) {                // final iteration: nothing staged, no reuse
      __syncthreads();             // drains stage vmcnt + protects buf reuse
      cur ^= 1;
    }
  }

  // epilogue: lane owns rows q = t0w + f*16 + li
#pragma unroll
  for (int f = 0; f < 2; f++) {
    const float inv = 1.f / lrow[f];
    bf16* orow = o + (long)(b * SEQ + t0w + f * 16 + li) * EMB + h * HDIM;
#pragma unroll
    for (int d = 0; d < 4; d++) {
      uint2 ow;
      ow.x = (bfbits(oacc[f][d][1] * inv) << 16) | bfbits(oacc[f][d][0] * inv);
      ow.y = (bfbits(oacc[f][d][3] * inv) << 16) | bfbits(oacc[f][d][2] * inv);
      *reinterpret_cast<uint2*>(&orow[d * 16 + lg * 4]) = ow;
    }
  }
}

// ---------------- host launcher ----------------
extern "C" void kernel_launch(void* const* d_in, const int* in_sizes, int n_in,
                              void* d_out, int out_size, void* d_ws, size_t ws_size,
                              hipStream_t stream) {
  (void)in_sizes; (void)n_in; (void)out_size;
  const int*   idx = (const int*)  d_in[0];
  const float* tok = (const float*)d_in[1];
  const float* pos = (const float*)d_in[2];
  const float* wq  = (const float*)d_in[3];
  const float* wk  = (const float*)d_in[4];
  const float* wv  = (const float*)d_in[5];
  const float* wo  = (const float*)d_in[6];
  const float* bo  = (const float*)d_in[7];
  const float* w1  = (const float*)d_in[8];
  const float* b1  = (const float*)d_in[9];
  const float* w2  = (const float*)d_in[10];
  const float* b2  = (const float*)d_in[11];
  const float* g1  = (const float*)d_in[12];
  const float* be1 = (const float*)d_in[13];
  const float* g2  = (const float*)d_in[14];
  const float* be2 = (const float*)d_in[15];
  const float* gf  = (const float*)d_in[16];
  const float* bef = (const float*)d_in[17];
  float* out = (float*)d_out;

  // allow 128 KB dynamic LDS (idempotent, host-side, capture-safe)
  (void)hipFuncSetAttribute((const void*)gemm256<0>, hipFuncAttributeMaxDynamicSharedMemorySize, 131072);
  (void)hipFuncSetAttribute((const void*)gemm256<2>, hipFuncAttributeMaxDynamicSharedMemorySize, 131072);
  (void)hipFuncSetAttribute((const void*)gemm256<3>, hipFuncAttributeMaxDynamicSharedMemorySize, 131072);

  char* p = (char*)d_ws;
  auto take = [&p](size_t bytes) { char* r = p; p += (bytes + 255) & ~(size_t)255; return r; };
  float* xf   = (float*)take((size_t)MROWS * EMB * 4);
  bf16*  hb   = (bf16*) take((size_t)MROWS * EMB * 2);
  bf16*  qkvb = (bf16*) take((size_t)MROWS * QKVSTR * 2);
  bf16*  vtb  = (bf16*) take((size_t)MROWS * EMB * 2);
  bf16*  ab   = (bf16*) take((size_t)MROWS * EMB * 2);
  bf16*  fb   = (bf16*) take((size_t)MROWS * FFND * 2);
  bf16*  tokT = (bf16*) take((size_t)VOCAB * EMB * 2);

  // weight-transpose pack: all 8 layers up front if workspace allows
  const size_t used_fixed = (size_t)(p - (char*)d_ws);
  const bool prepass = ws_size >= used_fixed + (size_t)LAYERS * WT_LAYER * 2 + 4096;
  bf16* wT = (bf16*)take((size_t)(prepass ? LAYERS : 1) * WT_LAYER * 2);

  k_f32_to_bf16<<<2048, 256, 0, stream>>>(tok, tokT, (long)VOCAB * EMB / 4);
  k_embed<<<MROWS, 256, 0, stream>>>(idx, tok, pos, xf);

  const dim3 tb(32, 8);
  if (prepass)
    k_transpose_wall<<<12288 * LAYERS, tb, 0, stream>>>(wq, wk, wv, wo, w1, w2, wT);

  for (int l = 0; l < LAYERS; l++) {
    const size_t we = (size_t)l * EMB * EMB;
    const size_t wfo = (size_t)l * EMB * FFND;
    if (!prepass)
      k_transpose_wall<<<12288, tb, 0, stream>>>(wq + we, wk + we, wv + we, wo + we,
                                                 w1 + wfo, w2 + wfo, wT);
    bf16* const wL    = wT + (prepass ? (long)l * WT_LAYER : 0);
    bf16* const qkvTl = wL + WT_QKV;
    bf16* const woTl  = wL + WT_WO;
    bf16* const w1Tl  = wL + WT_W1;
    bf16* const w2Tl  = wL + WT_W2;

    k_layernorm<<<MROWS / 4, 256, 0, stream>>>(xf, g1 + l * EMB, be1 + l * EMB, hb);
    gemm256<0><<<dim3(QKVSTR / 256, MROWS / 256), 512, 131072, stream>>>(
        hb, qkvTl, MROWS, QKVSTR, EMB, qkvb, nullptr, vtb, nullptr);
    k_attn<<<dim3(SEQ / 128, NBATCH * HEADS), 256, 0, stream>>>(qkvb, vtb, ab);
    gemm_bt<<<dim3(EMB / BN, MROWS / BM, 2), 256, 0, stream>>>(ab, woTl, MROWS, EMB, EMB, xf, bo + l * EMB);
    k_layernorm<<<MROWS / 4, 256, 0, stream>>>(xf, g2 + l * EMB, be2 + l * EMB, hb);
    gemm256<2><<<dim3(FFND / 256, MROWS / 256), 512, 131072, stream>>>(
        hb, w1Tl, MROWS, FFND, EMB, fb, b1 + l * FFND, nullptr, nullptr);
    gemm_bt<<<dim3(EMB / BN, MROWS / BM, 2), 256, 0, stream>>>(fb, w2Tl, MROWS, EMB, FFND, xf, b2 + l * EMB);
  }

  k_layernorm<<<MROWS / 4, 256, 0, stream>>>(xf, gf, bef, hb);
  // logits: proven single-pipeline form; grid 125x16 = 2000 blocks (%8==0)
  gemm256<3><<<dim3(VOCAB / 256, MROWS / 256), 512, 131072, stream>>>(
      hb, tokT, MROWS, VOCAB, EMB, nullptr, nullptr, nullptr, out);
}

// Round 15
// 2543.896 us; speedup vs baseline: 1.0476x; 1.0393x over previous
//
#include <hip/hip_runtime.h>
#include <hip/hip_bf16.h>
#include <cstdint>
#include <cstddef>

#define LAYERS   8
#define HEADS    16
#define EMB      1024
#define FFND     4096
#define VOCAB    32000
#define SEQ      2048
#define NBATCH   2
#define MROWS    (NBATCH*SEQ)   // 4096
#define HDIM     64
#define QKVSTR   3072
#define LN_EPS   1e-5f
#define QSCALE   0.18033688011112042f   // (1/sqrt(64)) * log2(e)

// transposed-weight pack layout (elements)
#define WT_QKV   0
#define WT_WO    3145728
#define WT_W1    4194304
#define WT_W2    8388608
#define WT_LAYER 12582912

typedef __hip_bfloat16 bf16;
typedef short short8 __attribute__((ext_vector_type(8)));   // 8 x bf16 bits (4 VGPRs)
typedef float f32x4  __attribute__((ext_vector_type(4)));

// ---------------- async global->LDS (16B per lane) ----------------
__device__ __forceinline__ void async_copy16(const bf16* g, bf16* l) {
  __builtin_amdgcn_global_load_lds(
      (const __attribute__((address_space(1))) void*)g,
      (__attribute__((address_space(3))) void*)l, 16, 0, 0);
}

__device__ __forceinline__ uint32_t bfbits(float x) {
  __hip_bfloat16 h = __float2bfloat16(x);
  return (uint32_t)reinterpret_cast<uint16_t&>(h);
}

// ---------------- fp32 -> bf16 bulk convert ----------------
struct __align__(8) B4 { bf16 a, b, c, d; };

__global__ void k_f32_to_bf16(const float* __restrict__ in, bf16* __restrict__ out, long n4) {
  long i = (long)blockIdx.x * blockDim.x + threadIdx.x;
  const long stride = (long)gridDim.x * blockDim.x;
  for (; i < n4; i += stride) {
    float4 v = reinterpret_cast<const float4*>(in)[i];
    B4 o;
    o.a = __float2bfloat16(v.x);
    o.b = __float2bfloat16(v.y);
    o.c = __float2bfloat16(v.z);
    o.d = __float2bfloat16(v.w);
    reinterpret_cast<B4*>(out)[i] = o;
  }
}

// ---------------- embedding: x = tok_emb[idx] + pos_emb ----------------
__global__ void k_embed(const int* __restrict__ idx, const float* __restrict__ tok,
                        const float* __restrict__ pos, float* __restrict__ x) {
  const int row  = blockIdx.x;           // 0..4095 = b*SEQ + t
  const int tpos = row & (SEQ - 1);
  const int token = idx[row];
  const float4* te = (const float4*)(tok + (long)token * EMB);
  const float4* pe = (const float4*)(pos + (long)tpos * EMB);
  float4* xo = (float4*)(x + (long)row * EMB);
  for (int i = threadIdx.x; i < EMB / 4; i += blockDim.x) {
    float4 a = te[i], b = pe[i];
    a.x += b.x; a.y += b.y; a.z += b.z; a.w += b.w;
    xo[i] = a;
  }
}

// ---------------- weight transpose: fp32 [K][N] -> bf16 [N][K], one layer ----------------
// Per-layer (NOT prepass): keeps the transposed weights L2/L3-hot for the
// GEMMs that consume them next (round-14 lesson: an 8-layer prepass evicts
// everything from L3 and costs ~90 us).
__global__ void k_transpose_wall(const float* __restrict__ wq, const float* __restrict__ wk,
                                 const float* __restrict__ wv, const float* __restrict__ wo,
                                 const float* __restrict__ w1, const float* __restrict__ w2,
                                 bf16* __restrict__ wT) {
  __shared__ float tile[32][33];
  const int bid = blockIdx.x;
  const float* in; bf16* out; int K, N, bx, by;
  if (bid < 4096) {
    const int rest = bid & 1023;
    switch (bid >> 10) {
      case 0:  in = wq; out = wT + WT_QKV;               break;
      case 1:  in = wk; out = wT + WT_QKV + EMB * EMB;   break;
      case 2:  in = wv; out = wT + WT_QKV + 2 * EMB * EMB; break;
      default: in = wo; out = wT + WT_WO;                break;
    }
    K = EMB; N = EMB; bx = rest & 31; by = rest >> 5;
  } else if (bid < 8192) {
    const int rest = bid - 4096;
    in = w1; out = wT + WT_W1; K = EMB; N = FFND;
    bx = rest & 127; by = rest >> 7;
  } else {
    const int rest = bid - 8192;
    in = w2; out = wT + WT_W2; K = FFND; N = EMB;
    bx = rest & 31; by = rest >> 5;
  }
  const int n0 = bx * 32, k0 = by * 32;
  const int tx = threadIdx.x, ty = threadIdx.y;   // (32,8)
  for (int i = 0; i < 32; i += 8)
    tile[ty + i][tx] = in[(long)(k0 + ty + i) * N + n0 + tx];
  __syncthreads();
  for (int i = 0; i < 32; i += 8)
    out[(long)(n0 + ty + i) * K + k0 + tx] = __float2bfloat16(tile[tx][ty + i]);
}

// ---------------- LayerNorm: wave-per-row (4 rows/block), fp32 in -> bf16 out ----------------
__global__ __launch_bounds__(256)
void k_layernorm(const float* __restrict__ x, const float* __restrict__ g,
                 const float* __restrict__ b, bf16* __restrict__ out) {
  const int wid  = threadIdx.x >> 6;
  const int lane = threadIdx.x & 63;
  const long row = (long)blockIdx.x * 4 + wid;
  const float4* xr = (const float4*)(x + row * EMB);
  float4 xv[4];
  float s = 0.f, sq = 0.f;
#pragma unroll
  for (int i = 0; i < 4; i++) {
    xv[i] = xr[lane + i * 64];
    s  += xv[i].x + xv[i].y + xv[i].z + xv[i].w;
    sq += xv[i].x * xv[i].x + xv[i].y * xv[i].y + xv[i].z * xv[i].z + xv[i].w * xv[i].w;
  }
#pragma unroll
  for (int m = 1; m < 64; m <<= 1) { s += __shfl_xor(s, m); sq += __shfl_xor(sq, m); }
  const float mean = s * (1.f / EMB);
  const float var  = sq * (1.f / EMB) - mean * mean;
  const float rstd = rsqrtf(var + LN_EPS);
  const float4* gv = (const float4*)g;
  const float4* bv = (const float4*)b;
  bf16* orow = out + row * EMB;
#pragma unroll
  for (int i = 0; i < 4; i++) {
    const int c4 = lane + i * 64;
    const float4 gg = gv[c4], bb = bv[c4];
    uint2 o;
    o.x = (bfbits((xv[i].y - mean) * rstd * gg.y + bb.y) << 16) |
           bfbits((xv[i].x - mean) * rstd * gg.x + bb.x);
    o.y = (bfbits((xv[i].w - mean) * rstd * gg.w + bb.w) << 16) |
           bfbits((xv[i].z - mean) * rstd * gg.z + bb.z);
    *reinterpret_cast<uint2*>(&orow[c4 * 4]) = o;
  }
}

// ======================================================================
// 256x256 GEMM, 2 super-phases/tile. C[M,N] = A[M,K]*Bt[N,K]^T
// MODE 0 (QKV): Q cols (<EMB) pre-scaled by QSCALE -> outB; K cols -> outB;
//   V cols (>=2*EMB) written TRANSPOSED into vt_out[bh*64+d][t].
// MODE 2: outB = bf16(relu(acc+bias)); MODE 3: outF = acc (fp32, single
// epilogue at kernel end -- stores must never interleave the vmcnt ring).
// ======================================================================
template<int MODE>
__global__ __launch_bounds__(512, 2)
void gemm256(const bf16* __restrict__ A, const bf16* __restrict__ Bt,
             int M, int N, int K,
             bf16* __restrict__ outB, const float* __restrict__ bias,
             bf16* __restrict__ vt_out, float* __restrict__ outF) {
  extern __shared__ __align__(16) char smem[];   // 128 KB
  char* const smA = smem;
  char* const smB = smem + 65536;

  const int t    = threadIdx.x;
  const int lane = t & 63;
  const int wid  = t >> 6;
  const int wr   = wid >> 2;          // 0..1 : A half (rows wr*128..)
  const int wc   = wid & 3;           // 0..3 : cols wc*64.. ; B half = wc>>1
  const int lrow = lane & 15;
  const int ks16 = (lane >> 4) * 16;  // k-slice byte offset
  const int rswz = (lrow & 7) << 4;   // read-side XOR

  // linearize + bijective XCD chunk swizzle (nwg % 8 == 0)
  int lin = blockIdx.x * gridDim.y + blockIdx.y;
  { const int nwg = gridDim.x * gridDim.y; const int per = nwg >> 3;
    lin = (lin & 7) * per + (lin >> 3); }
  const int gx8  = gridDim.x * 8;
  const int half = lin / gx8;
  const int rem  = lin - half * gx8;
  const long bm  = (long)(half * 8 + (rem & 7)) * 256;
  const long bn  = (long)(rem >> 3) * 256;
  const int NT = K >> 6;

  const int row0 = wid * 8 + (lane >> 3);               // dest row of load 0
  const int col0 = ((lane & 7) ^ (lane >> 3)) * 8;      // pre-swizzled src col
  const int row1 = row0 + 64;                           // load 1: row+64, same col
  const int dst0 = wid * 1024;
  const int dst1 = 8192 + wid * 1024;
  const bf16* const gA = A + bm * K;
  const bf16* const gB = Bt + bn * K;

  auto STG = [&](char* ring, const bf16* g_, int tile, int h) {
    char* slot = ring + (((tile << 1) + h) & 3) * 16384;
    const bf16* sb = g_ + ((long)h * 128) * K + (long)tile * 64;
    async_copy16(sb + (long)row0 * K + col0, (bf16*)(slot + dst0));
    async_copy16(sb + (long)row1 * K + col0, (bf16*)(slot + dst1));
  };
  auto LDA8 = [&](int u, int m, int kk) -> short8 {
    const int off = (m * 16 + lrow) * 128 + ((kk * 64 + ks16) ^ rswz);
    return *reinterpret_cast<const short8*>(smA + (((u << 1) + wr) & 3) * 16384 + off);
  };
  auto LDB8 = [&](int u, int n, int kk) -> short8 {
    const int off = ((wc & 1) * 64 + n * 16 + lrow) * 128 + ((kk * 64 + ks16) ^ rswz);
    return *reinterpret_cast<const short8*>(smB + (((u << 1) + (wc >> 1)) & 3) * 16384 + off);
  };
#define MF(a_, b_, c_) __builtin_amdgcn_mfma_f32_16x16x32_bf16(a_, b_, c_, 0, 0, 0)

  f32x4 acc[8][4] = {};

  // prologue: B(0) A(0) B(1); last 4 loads (B(1)) may stay in flight
  STG(smB, gB, 0, 0); STG(smB, gB, 0, 1);
  STG(smA, gA, 0, 0); STG(smA, gA, 0, 1);
  STG(smB, gB, 1, 0); STG(smB, gB, 1, 1);
  asm volatile("s_waitcnt vmcnt(4)" ::: "memory");
  __builtin_amdgcn_s_barrier();

  short8 bq[4][2];
  for (int u = 0; u < NT; u++) {
    // ---- super-phase A: read B(all) + A(m0..m3); stage A(u+1) ----
#pragma unroll
    for (int n = 0; n < 4; n++) { bq[n][0] = LDB8(u, n, 0); bq[n][1] = LDB8(u, n, 1); }
    short8 a0 = LDA8(u, 0, 0), a1 = LDA8(u, 0, 1), a2 = LDA8(u, 1, 0), a3 = LDA8(u, 1, 1);
    short8 a4 = LDA8(u, 2, 0), a5 = LDA8(u, 2, 1), a6 = LDA8(u, 3, 0), a7 = LDA8(u, 3, 1);
    if (u + 1 < NT) { STG(smA, gA, u + 1, 0); STG(smA, gA, u + 1, 1); }
    __builtin_amdgcn_s_barrier();
    asm volatile("s_waitcnt lgkmcnt(0)" ::: "memory");
    __builtin_amdgcn_sched_barrier(0);
    __builtin_amdgcn_s_setprio(1);
#pragma unroll
    for (int n = 0; n < 4; n++) {
      acc[0][n] = MF(a0, bq[n][0], acc[0][n]); acc[0][n] = MF(a1, bq[n][1], acc[0][n]);
      acc[1][n] = MF(a2, bq[n][0], acc[1][n]); acc[1][n] = MF(a3, bq[n][1], acc[1][n]);
      acc[2][n] = MF(a4, bq[n][0], acc[2][n]); acc[2][n] = MF(a5, bq[n][1], acc[2][n]);
      acc[3][n] = MF(a6, bq[n][0], acc[3][n]); acc[3][n] = MF(a7, bq[n][1], acc[3][n]);
    }
    __builtin_amdgcn_s_setprio(0);
    __builtin_amdgcn_s_barrier();

    // ---- super-phase B: read A(m4..m7); stage B(u+2); tile-end wait ----
    a0 = LDA8(u, 4, 0); a1 = LDA8(u, 4, 1); a2 = LDA8(u, 5, 0); a3 = LDA8(u, 5, 1);
    a4 = LDA8(u, 6, 0); a5 = LDA8(u, 6, 1); a6 = LDA8(u, 7, 0); a7 = LDA8(u, 7, 1);
    if (u + 2 < NT) { STG(smB, gB, u + 2, 0); STG(smB, gB, u + 2, 1); }
    __builtin_amdgcn_s_barrier();
    asm volatile("s_waitcnt lgkmcnt(0)" ::: "memory");
    __builtin_amdgcn_sched_barrier(0);
    __builtin_amdgcn_s_setprio(1);
#pragma unroll
    for (int n = 0; n < 4; n++) {
      acc[4][n] = MF(a0, bq[n][0], acc[4][n]); acc[4][n] = MF(a1, bq[n][1], acc[4][n]);
      acc[5][n] = MF(a2, bq[n][0], acc[5][n]); acc[5][n] = MF(a3, bq[n][1], acc[5][n]);
      acc[6][n] = MF(a4, bq[n][0], acc[6][n]); acc[6][n] = MF(a5, bq[n][1], acc[6][n]);
      acc[7][n] = MF(a6, bq[n][0], acc[7][n]); acc[7][n] = MF(a7, bq[n][1], acc[7][n]);
    }
    __builtin_amdgcn_s_setprio(0);
    if (u + 2 < NT) { asm volatile("s_waitcnt vmcnt(4)" ::: "memory"); }
    else            { asm volatile("s_waitcnt vmcnt(0)" ::: "memory"); }
    __builtin_amdgcn_s_barrier();
  }

  // epilogue (single, at kernel end)
  const long rb = bm + wr * 128 + (lane >> 4) * 4;
  const long cb = bn + wc * 64 + lrow;
#pragma unroll
  for (int m = 0; m < 8; m++) {
#pragma unroll
    for (int n = 0; n < 4; n++) {
      const long col = cb + n * 16;
      if (MODE == 0 && col >= 2 * EMB) {
        // V slice: write transposed into vt_out[(b*16+h)*64+d][t], 4 consecutive t
        const int  dc = (int)(col - 2 * EMB);
        const long t0 = rb + m * 16;
        const long vr = ((t0 >> 11) * HEADS + (dc >> 6)) * (long)HDIM + (dc & 63);
        uint2 pv;
        pv.x = (bfbits(acc[m][n][1]) << 16) | bfbits(acc[m][n][0]);
        pv.y = (bfbits(acc[m][n][3]) << 16) | bfbits(acc[m][n][2]);
        *reinterpret_cast<uint2*>(&vt_out[vr * SEQ + (t0 & (SEQ - 1))]) = pv;
      } else {
#pragma unroll
        for (int r = 0; r < 4; r++) {
          const long row = rb + m * 16 + r;
          float vv = acc[m][n][r];
          if (MODE == 0) {
            if (col < EMB) vv *= QSCALE;     // pre-scale Q slice for attention
            outB[row * N + col] = __float2bfloat16(vv);
          } else if (MODE == 2) {
            vv += bias[col];
            outB[row * N + col] = __float2bfloat16(vv > 0.f ? vv : 0.f);
          } else {
            outF[row * N + col] = vv;
          }
        }
      }
    }
  }
#undef MF
}

// ---------------- 128x128 GEMM, split-K=2 + 2-phase dbuf ----------------
#define BM 128
#define BN 128
#define BK 32

__global__ __launch_bounds__(256)
void gemm_bt(const bf16* __restrict__ A, const bf16* __restrict__ Bt,
             int M, int N, int K,
             float* __restrict__ outF, const float* __restrict__ bias) {
  __shared__ __align__(16) bf16 lA[2][BM * BK];
  __shared__ __align__(16) bf16 lB[2][BN * BK];
  const int t    = threadIdx.x;
  const int lane = t & 63;
  const int wid  = t >> 6;
  const int wr   = wid >> 1;
  const int wc   = wid & 1;
  const long bm  = (long)blockIdx.y * BM;
  const long bn  = (long)blockIdx.x * BN;
  const int  kz  = blockIdx.z;
  const int  Kh  = K >> 1;

  f32x4 acc[4][4] = {};

  const long arow = t >> 2;                               // 0..63
  const int  acol = (((t & 3) ^ ((t >> 2) & 3)) * 8);     // pre-swizzled src col
  const bf16* gA = A  + (bm + arow) * K + kz * Kh + acol;
  const bf16* gB = Bt + (bn + arow) * K + kz * Kh + acol;
  const long astep = 64L * K;

  auto STGBT = [&](int buf, int k0) {
    async_copy16(gA + k0,         &lA[buf][wid * 512]);
    async_copy16(gA + k0 + astep, &lA[buf][wid * 512 + 2048]);
    async_copy16(gB + k0,         &lB[buf][wid * 512]);
    async_copy16(gB + k0 + astep, &lB[buf][wid * 512 + 2048]);
  };

  STGBT(0, 0);
  __syncthreads();

  int cur = 0;
  for (int k0 = 0; k0 < Kh; k0 += BK) {
    if (k0 + BK < Kh) STGBT(cur ^ 1, k0 + BK);   // overlaps with compute below

    const int ksel = (((lane >> 4) ^ (lane & 3)) * 8);    // swizzled read col
    short8 af[4], bfv[4];
#pragma unroll
    for (int i = 0; i < 4; i++) {
      af[i]  = *reinterpret_cast<const short8*>(&lA[cur][(wr * 64 + i * 16 + (lane & 15)) * BK + ksel]);
      bfv[i] = *reinterpret_cast<const short8*>(&lB[cur][(wc * 64 + i * 16 + (lane & 15)) * BK + ksel]);
    }
#pragma unroll
    for (int i = 0; i < 4; i++)
#pragma unroll
      for (int j = 0; j < 4; j++)
        acc[i][j] = __builtin_amdgcn_mfma_f32_16x16x32_bf16(af[i], bfv[j], acc[i][j], 0, 0, 0);
    __syncthreads();   // drains next-tile stage; protects cur buffer reuse
    cur ^= 1;
  }

  const long rbase = bm + wr * 64 + (lane >> 4) * 4;
  const long cbase = bn + wc * 64 + (lane & 15);
#pragma unroll
  for (int i = 0; i < 4; i++) {
#pragma unroll
    for (int j = 0; j < 4; j++) {
      const long col = cbase + j * 16;
      const float bv = kz ? 0.f : bias[col];
#pragma unroll
      for (int r = 0; r < 4; r++) {
        const long row = rbase + i * 16 + r;
        unsafeAtomicAdd(&outF[row * N + col], acc[i][j][r] + bv);
      }
    }
  }
}

// ---------------- flash attention (causal), 2 q-frags/wave, defer-max, paired balance ----------------
__global__ __launch_bounds__(256)
void k_attn(const bf16* __restrict__ qkv, const bf16* __restrict__ vt, bf16* __restrict__ o) {
  const int bh = blockIdx.y;
  const int qt = (bh & 16) ? blockIdx.x : (gridDim.x - 1 - blockIdx.x);
  const int b  = bh >> 4;
  const int h  = bh & 15;
  const int t0b = qt * 128;
  const int tid = threadIdx.x;
  const int w    = tid >> 6;
  const int lane = tid & 63;
  const int lg = lane >> 4;            // 0..3
  const int li = lane & 15;
  const int t0w = t0b + w * 32;        // frag f rows: t0w + f*16 + li

  __shared__ __align__(16) bf16 Kl[2][64 * 64];
  __shared__ __align__(16) bf16 Vl[2][64 * 64];
  __shared__ __align__(16) bf16 Pl[4][32 * 64];   // per-wave P[q][k], swizzled

  const bf16* qbase = qkv + (long)(b * SEQ) * QKVSTR + h * HDIM;   // Q pre-scaled by QSCALE
  const bf16* kbase = qkv + (long)(b * SEQ) * QKVSTR + EMB + h * HDIM;
  const bf16* vbase = vt + (long)bh * HDIM * SEQ;

  short8 qf[2][2];
#pragma unroll
  for (int f = 0; f < 2; f++) {
    const bf16* qrow = qbase + (long)(t0w + f * 16 + li) * QKVSTR;
    qf[f][0] = *reinterpret_cast<const short8*>(&qrow[lg * 8]);
    qf[f][1] = *reinterpret_cast<const short8*>(&qrow[32 + lg * 8]);
  }

  f32x4 oacc[2][4] = {};
  float mrow[2] = {-1e30f, -1e30f}, lrow[2] = {0.f, 0.f};

  const int nkt = (t0b >> 6) + 1;            // last k-tile index (diag spans 2 tiles)
  const int l8  = lane >> 3;                 // 0..7
  const int sl8 = ((lane & 7) ^ l8) * 8;     // pre-swizzled source slot (rule 21)

  char* const Pw = (char*)&Pl[w][0];
  const int pswz = (li & 7) << 4;

  // prologue: stage tile 0 into buffer 0
#pragma unroll
  for (int sh = 0; sh < 2; sh++) {
    const int r = sh * 32 + w * 8 + l8;
    async_copy16(kbase + (long)r * QKVSTR + sl8, &Kl[0][(sh * 32 + w * 8) * 64]);
    async_copy16(vbase + (long)r * SEQ + sl8,    &Vl[0][(sh * 32 + w * 8) * 64]);
  }
  __syncthreads();

  int cur = 0;
  for (int kt = 0; kt <= nkt; kt++) {
    const int s0 = kt * 64;
    if (kt < nkt) {                          // stage next tile
      const int s0n = s0 + 64;
      bf16* Kn = &Kl[cur ^ 1][0];
      bf16* Vn = &Vl[cur ^ 1][0];
#pragma unroll
      for (int sh = 0; sh < 2; sh++) {
        const int r = sh * 32 + w * 8 + l8;
        async_copy16(kbase + (long)(s0n + r) * QKVSTR + sl8, Kn + (sh * 32 + w * 8) * 64);
        async_copy16(vbase + (long)r * SEQ + s0n + sl8,      Vn + (sh * 32 + w * 8) * 64);
      }
    }

    // S^T = mfma(K, Q) — Q already carries QSCALE (exp2 domain)
    f32x4 s[2][4] = {};
#pragma unroll
    for (int kk = 0; kk < 2; kk++)
#pragma unroll
      for (int sf = 0; sf < 4; sf++) {
        const short8 kf = *reinterpret_cast<const short8*>(
            &Kl[cur][(sf * 16 + li) * 64 + ((((kk << 2) | lg) ^ (li & 7)) * 8)]);
        s[0][sf] = __builtin_amdgcn_mfma_f32_16x16x32_bf16(kf, qf[0][kk], s[0][sf], 0, 0, 0);
        s[1][sf] = __builtin_amdgcn_mfma_f32_16x16x32_bf16(kf, qf[1][kk], s[1][sf], 0, 0, 0);
      }

    const bool diag = (kt >= nkt - 1);       // tiles < nkt-1 provably unmasked
    if (diag) {
#pragma unroll
      for (int f = 0; f < 2; f++)
#pragma unroll
        for (int sf = 0; sf < 4; sf++)
#pragma unroll
          for (int r = 0; r < 4; r++)
            if (s0 + sf * 16 + lg * 4 + r > t0w + f * 16 + li) s[f][sf][r] = -1e30f;
    }

    // per-lane softmax per frag, defer-max (T13, THR=8 in exp2 domain)
#pragma unroll
    for (int f = 0; f < 2; f++) {
      float mx = -1e30f;
#pragma unroll
      for (int sf = 0; sf < 4; sf++)
        mx = fmaxf(mx, fmaxf(fmaxf(s[f][sf][0], s[f][sf][1]), fmaxf(s[f][sf][2], s[f][sf][3])));
      mx = fmaxf(mx, __shfl_xor(mx, 16));
      mx = fmaxf(mx, __shfl_xor(mx, 32));
      if (__any(mx > mrow[f] + 8.f)) {       // rescale only when max grew materially
        const float mnew = fmaxf(mrow[f], mx);
        const float alpha = exp2f(mrow[f] - mnew);
        mrow[f] = mnew;
        lrow[f] *= alpha;
#pragma unroll
        for (int d = 0; d < 4; d++)
#pragma unroll
          for (int r = 0; r < 4; r++) oacc[f][d][r] *= alpha;
      }
      float rs = 0.f;
#pragma unroll
      for (int sf = 0; sf < 4; sf++)
#pragma unroll
        for (int r = 0; r < 4; r++) {
          const float pv = exp2f(s[f][sf][r] - mrow[f]);   // bounded by 2^8
          s[f][sf][r] = pv;
          rs += pv;
        }
      rs += __shfl_xor(rs, 16);
      rs += __shfl_xor(rs, 32);
      lrow[f] += rs;

      // P write: row f*16+li, 4 contiguous k per sf, 16B-granule swizzle
#pragma unroll
      for (int sf = 0; sf < 4; sf++) {
        uint2 pw2;
        pw2.x = (bfbits(s[f][sf][1]) << 16) | bfbits(s[f][sf][0]);
        pw2.y = (bfbits(s[f][sf][3]) << 16) | bfbits(s[f][sf][2]);
        *reinterpret_cast<uint2*>(Pw + (f * 16 + li) * 128 + ((sf * 32 + lg * 8) ^ pswz)) = pw2;
      }
    }

    // O^T += mfma(V, P^T); vf shared across frags
#pragma unroll
    for (int kk = 0; kk < 2; kk++) {
      const short8 pb0 = *reinterpret_cast<const short8*>(
          Pw + li * 128 + ((kk * 64 + lg * 16) ^ pswz));
      const short8 pb1 = *reinterpret_cast<const short8*>(
          Pw + (16 + li) * 128 + ((kk * 64 + lg * 16) ^ pswz));
#pragma unroll
      for (int d = 0; d < 4; d++) {
        const short8 vf = *reinterpret_cast<const short8*>(
            &Vl[cur][(d * 16 + li) * 64 + ((((kk << 2) | lg) ^ (li & 7)) * 8)]);
        oacc[0][d] = __builtin_amdgcn_mfma_f32_16x16x32_bf16(vf, pb0, oacc[0][d], 0, 0, 0);
        oacc[1][d] = __builtin_amdgcn_mfma_f32_16x16x32_bf16(vf, pb1, oacc[1][d], 0, 0, 0);
      }
    }

    if (kt < nkt) {                // final iteration: nothing staged, no reuse
      __syncthreads();             // drains stage vmcnt + protects buf reuse
      cur ^= 1;
    }
  }

  // epilogue: lane owns rows q = t0w + f*16 + li
#pragma unroll
  for (int f = 0; f < 2; f++) {
    const float inv = 1.f / lrow[f];
    bf16* orow = o + (long)(b * SEQ + t0w + f * 16 + li) * EMB + h * HDIM;
#pragma unroll
    for (int d = 0; d < 4; d++) {
      uint2 ow;
      ow.x = (bfbits(oacc[f][d][1] * inv) << 16) | bfbits(oacc[f][d][0] * inv);
      ow.y = (bfbits(oacc[f][d][3] * inv) << 16) | bfbits(oacc[f][d][2] * inv);
      *reinterpret_cast<uint2*>(&orow[d * 16 + lg * 4]) = ow;
    }
  }
}

// ---------------- host launcher ----------------
extern "C" void kernel_launch(void* const* d_in, const int* in_sizes, int n_in,
                              void* d_out, int out_size, void* d_ws, size_t ws_size,
                              hipStream_t stream) {
  (void)in_sizes; (void)n_in; (void)out_size; (void)ws_size;
  const int*   idx = (const int*)  d_in[0];
  const float* tok = (const float*)d_in[1];
  const float* pos = (const float*)d_in[2];
  const float* wq  = (const float*)d_in[3];
  const float* wk  = (const float*)d_in[4];
  const float* wv  = (const float*)d_in[5];
  const float* wo  = (const float*)d_in[6];
  const float* bo  = (const float*)d_in[7];
  const float* w1  = (const float*)d_in[8];
  const float* b1  = (const float*)d_in[9];
  const float* w2  = (const float*)d_in[10];
  const float* b2  = (const float*)d_in[11];
  const float* g1  = (const float*)d_in[12];
  const float* be1 = (const float*)d_in[13];
  const float* g2  = (const float*)d_in[14];
  const float* be2 = (const float*)d_in[15];
  const float* gf  = (const float*)d_in[16];
  const float* bef = (const float*)d_in[17];
  float* out = (float*)d_out;

  // allow 128 KB dynamic LDS (idempotent, host-side, capture-safe)
  (void)hipFuncSetAttribute((const void*)gemm256<0>, hipFuncAttributeMaxDynamicSharedMemorySize, 131072);
  (void)hipFuncSetAttribute((const void*)gemm256<2>, hipFuncAttributeMaxDynamicSharedMemorySize, 131072);
  (void)hipFuncSetAttribute((const void*)gemm256<3>, hipFuncAttributeMaxDynamicSharedMemorySize, 131072);

  char* p = (char*)d_ws;
  auto take = [&p](size_t bytes) { char* r = p; p += (bytes + 255) & ~(size_t)255; return r; };
  float* xf   = (float*)take((size_t)MROWS * EMB * 4);
  bf16*  hb   = (bf16*) take((size_t)MROWS * EMB * 2);
  bf16*  qkvb = (bf16*) take((size_t)MROWS * QKVSTR * 2);
  bf16*  vtb  = (bf16*) take((size_t)MROWS * EMB * 2);
  bf16*  ab   = (bf16*) take((size_t)MROWS * EMB * 2);
  bf16*  fb   = (bf16*) take((size_t)MROWS * FFND * 2);
  bf16*  tokT = (bf16*) take((size_t)VOCAB * EMB * 2);
  bf16*  wT   = (bf16*) take((size_t)WT_LAYER * 2);      // per-layer transposed pack

  k_f32_to_bf16<<<2048, 256, 0, stream>>>(tok, tokT, (long)VOCAB * EMB / 4);
  k_embed<<<MROWS, 256, 0, stream>>>(idx, tok, pos, xf);

  const dim3 tb(32, 8);

  for (int l = 0; l < LAYERS; l++) {
    const size_t we = (size_t)l * EMB * EMB;
    const size_t wfo = (size_t)l * EMB * FFND;
    k_transpose_wall<<<12288, tb, 0, stream>>>(wq + we, wk + we, wv + we, wo + we,
                                               w1 + wfo, w2 + wfo, wT);
    bf16* const qkvTl = wT + WT_QKV;
    bf16* const woTl  = wT + WT_WO;
    bf16* const w1Tl  = wT + WT_W1;
    bf16* const w2Tl  = wT + WT_W2;

    k_layernorm<<<MROWS / 4, 256, 0, stream>>>(xf, g1 + l * EMB, be1 + l * EMB, hb);
    gemm256<0><<<dim3(QKVSTR / 256, MROWS / 256), 512, 131072, stream>>>(
        hb, qkvTl, MROWS, QKVSTR, EMB, qkvb, nullptr, vtb, nullptr);
    k_attn<<<dim3(SEQ / 128, NBATCH * HEADS), 256, 0, stream>>>(qkvb, vtb, ab);
    gemm_bt<<<dim3(EMB / BN, MROWS / BM, 2), 256, 0, stream>>>(ab, woTl, MROWS, EMB, EMB, xf, bo + l * EMB);
    k_layernorm<<<MROWS / 4, 256, 0, stream>>>(xf, g2 + l * EMB, be2 + l * EMB, hb);
    gemm256<2><<<dim3(FFND / 256, MROWS / 256), 512, 131072, stream>>>(
        hb, w1Tl, MROWS, FFND, EMB, fb, b1 + l * FFND, nullptr, nullptr);
    gemm_bt<<<dim3(EMB / BN, MROWS / BM, 2), 256, 0, stream>>>(fb, w2Tl, MROWS, EMB, FFND, xf, b2 + l * EMB);
  }

  k_layernorm<<<MROWS / 4, 256, 0, stream>>>(xf, gf, bef, hb);
  // logits: proven single-pipeline form; grid 125x16 = 2000 blocks (%8==0)
  gemm256<3><<<dim3(VOCAB / 256, MROWS / 256), 512, 131072, stream>>>(
      hb, tokT, MROWS, VOCAB, EMB, nullptr, nullptr, nullptr, out);
}

// Round 16
// 2523.429 us; speedup vs baseline: 1.0561x; 1.0081x over previous
//
#include <hip/hip_runtime.h>
#include <hip/hip_bf16.h>
#include <cstdint>
#include <cstddef>

#define LAYERS   8
#define HEADS    16
#define EMB      1024
#define FFND     4096
#define VOCAB    32000
#define SEQ      2048
#define NBATCH   2
#define MROWS    (NBATCH*SEQ)   // 4096
#define HDIM     64
#define QKVSTR   3072
#define LN_EPS   1e-5f
#define QSCALE   0.18033688011112042f   // (1/sqrt(64)) * log2(e)

// transposed-weight pack layout (elements)
#define WT_QKV   0
#define WT_WO    3145728
#define WT_W1    4194304
#define WT_W2    8388608
#define WT_LAYER 12582912

typedef __hip_bfloat16 bf16;
typedef short short8 __attribute__((ext_vector_type(8)));   // 8 x bf16 bits (4 VGPRs)
typedef float f32x4  __attribute__((ext_vector_type(4)));

// ---------------- async global->LDS (16B per lane) ----------------
__device__ __forceinline__ void async_copy16(const bf16* g, bf16* l) {
  __builtin_amdgcn_global_load_lds(
      (const __attribute__((address_space(1))) void*)g,
      (__attribute__((address_space(3))) void*)l, 16, 0, 0);
}

__device__ __forceinline__ uint32_t bfbits(float x) {
  __hip_bfloat16 h = __float2bfloat16(x);
  return (uint32_t)reinterpret_cast<uint16_t&>(h);
}

// ---------------- fp32 -> bf16 bulk convert ----------------
struct __align__(8) B4 { bf16 a, b, c, d; };

__global__ void k_f32_to_bf16(const float* __restrict__ in, bf16* __restrict__ out, long n4) {
  long i = (long)blockIdx.x * blockDim.x + threadIdx.x;
  const long stride = (long)gridDim.x * blockDim.x;
  for (; i < n4; i += stride) {
    float4 v = reinterpret_cast<const float4*>(in)[i];
    B4 o;
    o.a = __float2bfloat16(v.x);
    o.b = __float2bfloat16(v.y);
    o.c = __float2bfloat16(v.z);
    o.d = __float2bfloat16(v.w);
    reinterpret_cast<B4*>(out)[i] = o;
  }
}

// ---------------- embedding: x = tok_emb[idx] + pos_emb ----------------
__global__ void k_embed(const int* __restrict__ idx, const float* __restrict__ tok,
                        const float* __restrict__ pos, float* __restrict__ x) {
  const int row  = blockIdx.x;           // 0..4095 = b*SEQ + t
  const int tpos = row & (SEQ - 1);
  const int token = idx[row];
  const float4* te = (const float4*)(tok + (long)token * EMB);
  const float4* pe = (const float4*)(pos + (long)tpos * EMB);
  float4* xo = (float4*)(x + (long)row * EMB);
  for (int i = threadIdx.x; i < EMB / 4; i += blockDim.x) {
    float4 a = te[i], b = pe[i];
    a.x += b.x; a.y += b.y; a.z += b.z; a.w += b.w;
    xo[i] = a;
  }
}

// ======================================================================
// Fused per-layer prep: weight transpose (blocks 0..12287) + LN1
// (blocks 12288..13311). Both are independent memory-bound streams;
// merging removes a launch and interleaves their latency bubbles.
// Per-layer (NOT an 8-layer prepass): keeps transposed weights L3-hot
// for the GEMMs that consume them (round-14 lesson: prepass cost ~90us).
// ======================================================================
__global__ __launch_bounds__(256)
void k_prep(const float* __restrict__ wq, const float* __restrict__ wk,
            const float* __restrict__ wv, const float* __restrict__ wo,
            const float* __restrict__ w1, const float* __restrict__ w2,
            bf16* __restrict__ wT,
            const float* __restrict__ x, const float* __restrict__ g,
            const float* __restrict__ b, bf16* __restrict__ outLN) {
  const int bid = blockIdx.x;
  if (bid < 12288) {
    // ---- weight transpose: fp32 [K][N] -> bf16 [N][K] ----
    __shared__ float tile[32][33];
    const float* in; bf16* out; int K, N, bx, by;
    if (bid < 4096) {
      const int rest = bid & 1023;
      switch (bid >> 10) {
        case 0:  in = wq; out = wT + WT_QKV;               break;
        case 1:  in = wk; out = wT + WT_QKV + EMB * EMB;   break;
        case 2:  in = wv; out = wT + WT_QKV + 2 * EMB * EMB; break;
        default: in = wo; out = wT + WT_WO;                break;
      }
      K = EMB; N = EMB; bx = rest & 31; by = rest >> 5;
    } else if (bid < 8192) {
      const int rest = bid - 4096;
      in = w1; out = wT + WT_W1; K = EMB; N = FFND;
      bx = rest & 127; by = rest >> 7;
    } else {
      const int rest = bid - 8192;
      in = w2; out = wT + WT_W2; K = FFND; N = EMB;
      bx = rest & 31; by = rest >> 5;
    }
    const int n0 = bx * 32, k0 = by * 32;
    const int tx = threadIdx.x & 31, ty = threadIdx.x >> 5;   // (32,8)
    for (int i = 0; i < 32; i += 8)
      tile[ty + i][tx] = in[(long)(k0 + ty + i) * N + n0 + tx];
    __syncthreads();
    for (int i = 0; i < 32; i += 8)
      out[(long)(n0 + ty + i) * K + k0 + tx] = __float2bfloat16(tile[tx][ty + i]);
  } else {
    // ---- LayerNorm: wave-per-row (4 rows/block), fp32 in -> bf16 out ----
    const int wid  = threadIdx.x >> 6;
    const int lane = threadIdx.x & 63;
    const long row = (long)(bid - 12288) * 4 + wid;
    const float4* xr = (const float4*)(x + row * EMB);
    float4 xv[4];
    float s = 0.f, sq = 0.f;
#pragma unroll
    for (int i = 0; i < 4; i++) {
      xv[i] = xr[lane + i * 64];
      s  += xv[i].x + xv[i].y + xv[i].z + xv[i].w;
      sq += xv[i].x * xv[i].x + xv[i].y * xv[i].y + xv[i].z * xv[i].z + xv[i].w * xv[i].w;
    }
#pragma unroll
    for (int m = 1; m < 64; m <<= 1) { s += __shfl_xor(s, m); sq += __shfl_xor(sq, m); }
    const float mean = s * (1.f / EMB);
    const float var  = sq * (1.f / EMB) - mean * mean;
    const float rstd = rsqrtf(var + LN_EPS);
    const float4* gv = (const float4*)g;
    const float4* bv = (const float4*)b;
    bf16* orow = outLN + row * EMB;
#pragma unroll
    for (int i = 0; i < 4; i++) {
      const int c4 = lane + i * 64;
      const float4 gg = gv[c4], bb = bv[c4];
      uint2 o;
      o.x = (bfbits((xv[i].y - mean) * rstd * gg.y + bb.y) << 16) |
             bfbits((xv[i].x - mean) * rstd * gg.x + bb.x);
      o.y = (bfbits((xv[i].w - mean) * rstd * gg.w + bb.w) << 16) |
             bfbits((xv[i].z - mean) * rstd * gg.z + bb.z);
      *reinterpret_cast<uint2*>(&orow[c4 * 4]) = o;
    }
  }
}

// ---------------- LayerNorm: wave-per-row (4 rows/block), fp32 in -> bf16 out ----------------
__global__ __launch_bounds__(256)
void k_layernorm(const float* __restrict__ x, const float* __restrict__ g,
                 const float* __restrict__ b, bf16* __restrict__ out) {
  const int wid  = threadIdx.x >> 6;
  const int lane = threadIdx.x & 63;
  const long row = (long)blockIdx.x * 4 + wid;
  const float4* xr = (const float4*)(x + row * EMB);
  float4 xv[4];
  float s = 0.f, sq = 0.f;
#pragma unroll
  for (int i = 0; i < 4; i++) {
    xv[i] = xr[lane + i * 64];
    s  += xv[i].x + xv[i].y + xv[i].z + xv[i].w;
    sq += xv[i].x * xv[i].x + xv[i].y * xv[i].y + xv[i].z * xv[i].z + xv[i].w * xv[i].w;
  }
#pragma unroll
  for (int m = 1; m < 64; m <<= 1) { s += __shfl_xor(s, m); sq += __shfl_xor(sq, m); }
  const float mean = s * (1.f / EMB);
  const float var  = sq * (1.f / EMB) - mean * mean;
  const float rstd = rsqrtf(var + LN_EPS);
  const float4* gv = (const float4*)g;
  const float4* bv = (const float4*)b;
  bf16* orow = out + row * EMB;
#pragma unroll
  for (int i = 0; i < 4; i++) {
    const int c4 = lane + i * 64;
    const float4 gg = gv[c4], bb = bv[c4];
    uint2 o;
    o.x = (bfbits((xv[i].y - mean) * rstd * gg.y + bb.y) << 16) |
           bfbits((xv[i].x - mean) * rstd * gg.x + bb.x);
    o.y = (bfbits((xv[i].w - mean) * rstd * gg.w + bb.w) << 16) |
           bfbits((xv[i].z - mean) * rstd * gg.z + bb.z);
    *reinterpret_cast<uint2*>(&orow[c4 * 4]) = o;
  }
}

// ======================================================================
// 256x256 GEMM, 2 super-phases/tile. C[M,N] = A[M,K]*Bt[N,K]^T
// MODE 0 (QKV): Q cols (<EMB) pre-scaled by QSCALE -> outB; K cols -> outB;
//   V cols (>=2*EMB) written TRANSPOSED into vt_out[bh*64+d][t].
// MODE 2: outB = bf16(relu(acc+bias)); MODE 3: outF = acc (fp32, single
// epilogue at kernel end -- stores must never interleave the vmcnt ring).
// ======================================================================
template<int MODE>
__global__ __launch_bounds__(512, 2)
void gemm256(const bf16* __restrict__ A, const bf16* __restrict__ Bt,
             int M, int N, int K,
             bf16* __restrict__ outB, const float* __restrict__ bias,
             bf16* __restrict__ vt_out, float* __restrict__ outF) {
  extern __shared__ __align__(16) char smem[];   // 128 KB
  char* const smA = smem;
  char* const smB = smem + 65536;

  const int t    = threadIdx.x;
  const int lane = t & 63;
  const int wid  = t >> 6;
  const int wr   = wid >> 2;          // 0..1 : A half (rows wr*128..)
  const int wc   = wid & 3;           // 0..3 : cols wc*64.. ; B half = wc>>1
  const int lrow = lane & 15;
  const int ks16 = (lane >> 4) * 16;  // k-slice byte offset
  const int rswz = (lrow & 7) << 4;   // read-side XOR

  // linearize + bijective XCD chunk swizzle (nwg % 8 == 0)
  int lin = blockIdx.x * gridDim.y + blockIdx.y;
  { const int nwg = gridDim.x * gridDim.y; const int per = nwg >> 3;
    lin = (lin & 7) * per + (lin >> 3); }
  const int gx8  = gridDim.x * 8;
  const int half = lin / gx8;
  const int rem  = lin - half * gx8;
  const long bm  = (long)(half * 8 + (rem & 7)) * 256;
  const long bn  = (long)(rem >> 3) * 256;
  const int NT = K >> 6;

  const int row0 = wid * 8 + (lane >> 3);               // dest row of load 0
  const int col0 = ((lane & 7) ^ (lane >> 3)) * 8;      // pre-swizzled src col
  const int row1 = row0 + 64;                           // load 1: row+64, same col
  const int dst0 = wid * 1024;
  const int dst1 = 8192 + wid * 1024;
  const bf16* const gA = A + bm * K;
  const bf16* const gB = Bt + bn * K;

  auto STG = [&](char* ring, const bf16* g_, int tile, int h) {
    char* slot = ring + (((tile << 1) + h) & 3) * 16384;
    const bf16* sb = g_ + ((long)h * 128) * K + (long)tile * 64;
    async_copy16(sb + (long)row0 * K + col0, (bf16*)(slot + dst0));
    async_copy16(sb + (long)row1 * K + col0, (bf16*)(slot + dst1));
  };
  auto LDA8 = [&](int u, int m, int kk) -> short8 {
    const int off = (m * 16 + lrow) * 128 + ((kk * 64 + ks16) ^ rswz);
    return *reinterpret_cast<const short8*>(smA + (((u << 1) + wr) & 3) * 16384 + off);
  };
  auto LDB8 = [&](int u, int n, int kk) -> short8 {
    const int off = ((wc & 1) * 64 + n * 16 + lrow) * 128 + ((kk * 64 + ks16) ^ rswz);
    return *reinterpret_cast<const short8*>(smB + (((u << 1) + (wc >> 1)) & 3) * 16384 + off);
  };
#define MF(a_, b_, c_) __builtin_amdgcn_mfma_f32_16x16x32_bf16(a_, b_, c_, 0, 0, 0)

  f32x4 acc[8][4] = {};

  // prologue: B(0) A(0) B(1); last 4 loads (B(1)) may stay in flight
  STG(smB, gB, 0, 0); STG(smB, gB, 0, 1);
  STG(smA, gA, 0, 0); STG(smA, gA, 0, 1);
  STG(smB, gB, 1, 0); STG(smB, gB, 1, 1);
  asm volatile("s_waitcnt vmcnt(4)" ::: "memory");
  __builtin_amdgcn_s_barrier();

  short8 bq[4][2];
  for (int u = 0; u < NT; u++) {
    // ---- super-phase A: read B(all) + A(m0..m3); stage A(u+1) ----
#pragma unroll
    for (int n = 0; n < 4; n++) { bq[n][0] = LDB8(u, n, 0); bq[n][1] = LDB8(u, n, 1); }
    short8 a0 = LDA8(u, 0, 0), a1 = LDA8(u, 0, 1), a2 = LDA8(u, 1, 0), a3 = LDA8(u, 1, 1);
    short8 a4 = LDA8(u, 2, 0), a5 = LDA8(u, 2, 1), a6 = LDA8(u, 3, 0), a7 = LDA8(u, 3, 1);
    if (u + 1 < NT) { STG(smA, gA, u + 1, 0); STG(smA, gA, u + 1, 1); }
    __builtin_amdgcn_s_barrier();
    asm volatile("s_waitcnt lgkmcnt(0)" ::: "memory");
    __builtin_amdgcn_sched_barrier(0);
    __builtin_amdgcn_s_setprio(1);
#pragma unroll
    for (int n = 0; n < 4; n++) {
      acc[0][n] = MF(a0, bq[n][0], acc[0][n]); acc[0][n] = MF(a1, bq[n][1], acc[0][n]);
      acc[1][n] = MF(a2, bq[n][0], acc[1][n]); acc[1][n] = MF(a3, bq[n][1], acc[1][n]);
      acc[2][n] = MF(a4, bq[n][0], acc[2][n]); acc[2][n] = MF(a5, bq[n][1], acc[2][n]);
      acc[3][n] = MF(a6, bq[n][0], acc[3][n]); acc[3][n] = MF(a7, bq[n][1], acc[3][n]);
    }
    __builtin_amdgcn_s_setprio(0);
    __builtin_amdgcn_s_barrier();

    // ---- super-phase B: read A(m4..m7); stage B(u+2); tile-end wait ----
    a0 = LDA8(u, 4, 0); a1 = LDA8(u, 4, 1); a2 = LDA8(u, 5, 0); a3 = LDA8(u, 5, 1);
    a4 = LDA8(u, 6, 0); a5 = LDA8(u, 6, 1); a6 = LDA8(u, 7, 0); a7 = LDA8(u, 7, 1);
    if (u + 2 < NT) { STG(smB, gB, u + 2, 0); STG(smB, gB, u + 2, 1); }
    __builtin_amdgcn_s_barrier();
    asm volatile("s_waitcnt lgkmcnt(0)" ::: "memory");
    __builtin_amdgcn_sched_barrier(0);
    __builtin_amdgcn_s_setprio(1);
#pragma unroll
    for (int n = 0; n < 4; n++) {
      acc[4][n] = MF(a0, bq[n][0], acc[4][n]); acc[4][n] = MF(a1, bq[n][1], acc[4][n]);
      acc[5][n] = MF(a2, bq[n][0], acc[5][n]); acc[5][n] = MF(a3, bq[n][1], acc[5][n]);
      acc[6][n] = MF(a4, bq[n][0], acc[6][n]); acc[6][n] = MF(a5, bq[n][1], acc[6][n]);
      acc[7][n] = MF(a6, bq[n][0], acc[7][n]); acc[7][n] = MF(a7, bq[n][1], acc[7][n]);
    }
    __builtin_amdgcn_s_setprio(0);
    if (u + 2 < NT) { asm volatile("s_waitcnt vmcnt(4)" ::: "memory"); }
    else            { asm volatile("s_waitcnt vmcnt(0)" ::: "memory"); }
    __builtin_amdgcn_s_barrier();
  }

  // epilogue (single, at kernel end)
  const long rb = bm + wr * 128 + (lane >> 4) * 4;
  const long cb = bn + wc * 64 + lrow;
#pragma unroll
  for (int m = 0; m < 8; m++) {
#pragma unroll
    for (int n = 0; n < 4; n++) {
      const long col = cb + n * 16;
      if (MODE == 0 && col >= 2 * EMB) {
        // V slice: write transposed into vt_out[(b*16+h)*64+d][t], 4 consecutive t
        const int  dc = (int)(col - 2 * EMB);
        const long t0 = rb + m * 16;
        const long vr = ((t0 >> 11) * HEADS + (dc >> 6)) * (long)HDIM + (dc & 63);
        uint2 pv;
        pv.x = (bfbits(acc[m][n][1]) << 16) | bfbits(acc[m][n][0]);
        pv.y = (bfbits(acc[m][n][3]) << 16) | bfbits(acc[m][n][2]);
        *reinterpret_cast<uint2*>(&vt_out[vr * SEQ + (t0 & (SEQ - 1))]) = pv;
      } else {
#pragma unroll
        for (int r = 0; r < 4; r++) {
          const long row = rb + m * 16 + r;
          float vv = acc[m][n][r];
          if (MODE == 0) {
            if (col < EMB) vv *= QSCALE;     // pre-scale Q slice for attention
            outB[row * N + col] = __float2bfloat16(vv);
          } else if (MODE == 2) {
            vv += bias[col];
            outB[row * N + col] = __float2bfloat16(vv > 0.f ? vv : 0.f);
          } else {
            outF[row * N + col] = vv;
          }
        }
      }
    }
  }
#undef MF
}

// ---------------- 128x128 GEMM, split-K=2 + 2-phase dbuf ----------------
#define BM 128
#define BN 128
#define BK 32

__global__ __launch_bounds__(256)
void gemm_bt(const bf16* __restrict__ A, const bf16* __restrict__ Bt,
             int M, int N, int K,
             float* __restrict__ outF, const float* __restrict__ bias) {
  __shared__ __align__(16) bf16 lA[2][BM * BK];
  __shared__ __align__(16) bf16 lB[2][BN * BK];
  const int t    = threadIdx.x;
  const int lane = t & 63;
  const int wid  = t >> 6;
  const int wr   = wid >> 1;
  const int wc   = wid & 1;
  const long bm  = (long)blockIdx.y * BM;
  const long bn  = (long)blockIdx.x * BN;
  const int  kz  = blockIdx.z;
  const int  Kh  = K >> 1;

  f32x4 acc[4][4] = {};

  const long arow = t >> 2;                               // 0..63
  const int  acol = (((t & 3) ^ ((t >> 2) & 3)) * 8);     // pre-swizzled src col
  const bf16* gA = A  + (bm + arow) * K + kz * Kh + acol;
  const bf16* gB = Bt + (bn + arow) * K + kz * Kh + acol;
  const long astep = 64L * K;

  auto STGBT = [&](int buf, int k0) {
    async_copy16(gA + k0,         &lA[buf][wid * 512]);
    async_copy16(gA + k0 + astep, &lA[buf][wid * 512 + 2048]);
    async_copy16(gB + k0,         &lB[buf][wid * 512]);
    async_copy16(gB + k0 + astep, &lB[buf][wid * 512 + 2048]);
  };

  STGBT(0, 0);
  __syncthreads();

  int cur = 0;
  for (int k0 = 0; k0 < Kh; k0 += BK) {
    if (k0 + BK < Kh) STGBT(cur ^ 1, k0 + BK);   // overlaps with compute below

    const int ksel = (((lane >> 4) ^ (lane & 3)) * 8);    // swizzled read col
    short8 af[4], bfv[4];
#pragma unroll
    for (int i = 0; i < 4; i++) {
      af[i]  = *reinterpret_cast<const short8*>(&lA[cur][(wr * 64 + i * 16 + (lane & 15)) * BK + ksel]);
      bfv[i] = *reinterpret_cast<const short8*>(&lB[cur][(wc * 64 + i * 16 + (lane & 15)) * BK + ksel]);
    }
#pragma unroll
    for (int i = 0; i < 4; i++)
#pragma unroll
      for (int j = 0; j < 4; j++)
        acc[i][j] = __builtin_amdgcn_mfma_f32_16x16x32_bf16(af[i], bfv[j], acc[i][j], 0, 0, 0);
    __syncthreads();   // drains next-tile stage; protects cur buffer reuse
    cur ^= 1;
  }

  const long rbase = bm + wr * 64 + (lane >> 4) * 4;
  const long cbase = bn + wc * 64 + (lane & 15);
#pragma unroll
  for (int i = 0; i < 4; i++) {
#pragma unroll
    for (int j = 0; j < 4; j++) {
      const long col = cbase + j * 16;
      const float bv = kz ? 0.f : bias[col];
#pragma unroll
      for (int r = 0; r < 4; r++) {
        const long row = rbase + i * 16 + r;
        unsafeAtomicAdd(&outF[row * N + col], acc[i][j][r] + bv);
      }
    }
  }
}

// ---------------- flash attention (causal), 2 q-frags/wave, defer-max, paired balance ----------------
__global__ __launch_bounds__(256)
void k_attn(const bf16* __restrict__ qkv, const bf16* __restrict__ vt, bf16* __restrict__ o) {
  const int bh = blockIdx.y;
  const int qt = (bh & 16) ? blockIdx.x : (gridDim.x - 1 - blockIdx.x);
  const int b  = bh >> 4;
  const int h  = bh & 15;
  const int t0b = qt * 128;
  const int tid = threadIdx.x;
  const int w    = tid >> 6;
  const int lane = tid & 63;
  const int lg = lane >> 4;            // 0..3
  const int li = lane & 15;
  const int t0w = t0b + w * 32;        // frag f rows: t0w + f*16 + li

  __shared__ __align__(16) bf16 Kl[2][64 * 64];
  __shared__ __align__(16) bf16 Vl[2][64 * 64];
  __shared__ __align__(16) bf16 Pl[4][32 * 64];   // per-wave P[q][k], swizzled

  const bf16* qbase = qkv + (long)(b * SEQ) * QKVSTR + h * HDIM;   // Q pre-scaled by QSCALE
  const bf16* kbase = qkv + (long)(b * SEQ) * QKVSTR + EMB + h * HDIM;
  const bf16* vbase = vt + (long)bh * HDIM * SEQ;

  short8 qf[2][2];
#pragma unroll
  for (int f = 0; f < 2; f++) {
    const bf16* qrow = qbase + (long)(t0w + f * 16 + li) * QKVSTR;
    qf[f][0] = *reinterpret_cast<const short8*>(&qrow[lg * 8]);
    qf[f][1] = *reinterpret_cast<const short8*>(&qrow[32 + lg * 8]);
  }

  f32x4 oacc[2][4] = {};
  float mrow[2] = {-1e30f, -1e30f}, lrow[2] = {0.f, 0.f};

  const int nkt = (t0b >> 6) + 1;            // last k-tile index (diag spans 2 tiles)
  const int l8  = lane >> 3;                 // 0..7
  const int sl8 = ((lane & 7) ^ l8) * 8;     // pre-swizzled source slot (rule 21)

  char* const Pw = (char*)&Pl[w][0];
  const int pswz = (li & 7) << 4;

  // prologue: stage tile 0 into buffer 0
#pragma unroll
  for (int sh = 0; sh < 2; sh++) {
    const int r = sh * 32 + w * 8 + l8;
    async_copy16(kbase + (long)r * QKVSTR + sl8, &Kl[0][(sh * 32 + w * 8) * 64]);
    async_copy16(vbase + (long)r * SEQ + sl8,    &Vl[0][(sh * 32 + w * 8) * 64]);
  }
  __syncthreads();

  int cur = 0;
  for (int kt = 0; kt <= nkt; kt++) {
    const int s0 = kt * 64;
    if (kt < nkt) {                          // stage next tile
      const int s0n = s0 + 64;
      bf16* Kn = &Kl[cur ^ 1][0];
      bf16* Vn = &Vl[cur ^ 1][0];
#pragma unroll
      for (int sh = 0; sh < 2; sh++) {
        const int r = sh * 32 + w * 8 + l8;
        async_copy16(kbase + (long)(s0n + r) * QKVSTR + sl8, Kn + (sh * 32 + w * 8) * 64);
        async_copy16(vbase + (long)r * SEQ + s0n + sl8,      Vn + (sh * 32 + w * 8) * 64);
      }
    }

    // S^T = mfma(K, Q) — Q already carries QSCALE (exp2 domain)
    f32x4 s[2][4] = {};
#pragma unroll
    for (int kk = 0; kk < 2; kk++)
#pragma unroll
      for (int sf = 0; sf < 4; sf++) {
        const short8 kf = *reinterpret_cast<const short8*>(
            &Kl[cur][(sf * 16 + li) * 64 + ((((kk << 2) | lg) ^ (li & 7)) * 8)]);
        s[0][sf] = __builtin_amdgcn_mfma_f32_16x16x32_bf16(kf, qf[0][kk], s[0][sf], 0, 0, 0);
        s[1][sf] = __builtin_amdgcn_mfma_f32_16x16x32_bf16(kf, qf[1][kk], s[1][sf], 0, 0, 0);
      }

    const bool diag = (kt >= nkt - 1);       // tiles < nkt-1 provably unmasked
    if (diag) {
#pragma unroll
      for (int f = 0; f < 2; f++)
#pragma unroll
        for (int sf = 0; sf < 4; sf++)
#pragma unroll
          for (int r = 0; r < 4; r++)
            if (s0 + sf * 16 + lg * 4 + r > t0w + f * 16 + li) s[f][sf][r] = -1e30f;
    }

    // per-lane softmax per frag, defer-max (T13, THR=8 in exp2 domain)
#pragma unroll
    for (int f = 0; f < 2; f++) {
      float mx = -1e30f;
#pragma unroll
      for (int sf = 0; sf < 4; sf++)
        mx = fmaxf(mx, fmaxf(fmaxf(s[f][sf][0], s[f][sf][1]), fmaxf(s[f][sf][2], s[f][sf][3])));
      mx = fmaxf(mx, __shfl_xor(mx, 16));
      mx = fmaxf(mx, __shfl_xor(mx, 32));
      if (__any(mx > mrow[f] + 8.f)) {       // rescale only when max grew materially
        const float mnew = fmaxf(mrow[f], mx);
        const float alpha = exp2f(mrow[f] - mnew);
        mrow[f] = mnew;
        lrow[f] *= alpha;
#pragma unroll
        for (int d = 0; d < 4; d++)
#pragma unroll
          for (int r = 0; r < 4; r++) oacc[f][d][r] *= alpha;
      }
      float rs = 0.f;
#pragma unroll
      for (int sf = 0; sf < 4; sf++)
#pragma unroll
        for (int r = 0; r < 4; r++) {
          const float pv = exp2f(s[f][sf][r] - mrow[f]);   // bounded by 2^8
          s[f][sf][r] = pv;
          rs += pv;
        }
      rs += __shfl_xor(rs, 16);
      rs += __shfl_xor(rs, 32);
      lrow[f] += rs;

      // P write: row f*16+li, 4 contiguous k per sf, 16B-granule swizzle
#pragma unroll
      for (int sf = 0; sf < 4; sf++) {
        uint2 pw2;
        pw2.x = (bfbits(s[f][sf][1]) << 16) | bfbits(s[f][sf][0]);
        pw2.y = (bfbits(s[f][sf][3]) << 16) | bfbits(s[f][sf][2]);
        *reinterpret_cast<uint2*>(Pw + (f * 16 + li) * 128 + ((sf * 32 + lg * 8) ^ pswz)) = pw2;
      }
    }

    // O^T += mfma(V, P^T); vf shared across frags
#pragma unroll
    for (int kk = 0; kk < 2; kk++) {
      const short8 pb0 = *reinterpret_cast<const short8*>(
          Pw + li * 128 + ((kk * 64 + lg * 16) ^ pswz));
      const short8 pb1 = *reinterpret_cast<const short8*>(
          Pw + (16 + li) * 128 + ((kk * 64 + lg * 16) ^ pswz));
#pragma unroll
      for (int d = 0; d < 4; d++) {
        const short8 vf = *reinterpret_cast<const short8*>(
            &Vl[cur][(d * 16 + li) * 64 + ((((kk << 2) | lg) ^ (li & 7)) * 8)]);
        oacc[0][d] = __builtin_amdgcn_mfma_f32_16x16x32_bf16(vf, pb0, oacc[0][d], 0, 0, 0);
        oacc[1][d] = __builtin_amdgcn_mfma_f32_16x16x32_bf16(vf, pb1, oacc[1][d], 0, 0, 0);
      }
    }

    if (kt < nkt) {                // final iteration: nothing staged, no reuse
      __syncthreads();             // drains stage vmcnt + protects buf reuse
      cur ^= 1;
    }
  }

  // epilogue: lane owns rows q = t0w + f*16 + li
#pragma unroll
  for (int f = 0; f < 2; f++) {
    const float inv = 1.f / lrow[f];
    bf16* orow = o + (long)(b * SEQ + t0w + f * 16 + li) * EMB + h * HDIM;
#pragma unroll
    for (int d = 0; d < 4; d++) {
      uint2 ow;
      ow.x = (bfbits(oacc[f][d][1] * inv) << 16) | bfbits(oacc[f][d][0] * inv);
      ow.y = (bfbits(oacc[f][d][3] * inv) << 16) | bfbits(oacc[f][d][2] * inv);
      *reinterpret_cast<uint2*>(&orow[d * 16 + lg * 4]) = ow;
    }
  }
}

// ---------------- host launcher ----------------
extern "C" void kernel_launch(void* const* d_in, const int* in_sizes, int n_in,
                              void* d_out, int out_size, void* d_ws, size_t ws_size,
                              hipStream_t stream) {
  (void)in_sizes; (void)n_in; (void)out_size; (void)ws_size;
  const int*   idx = (const int*)  d_in[0];
  const float* tok = (const float*)d_in[1];
  const float* pos = (const float*)d_in[2];
  const float* wq  = (const float*)d_in[3];
  const float* wk  = (const float*)d_in[4];
  const float* wv  = (const float*)d_in[5];
  const float* wo  = (const float*)d_in[6];
  const float* bo  = (const float*)d_in[7];
  const float* w1  = (const float*)d_in[8];
  const float* b1  = (const float*)d_in[9];
  const float* w2  = (const float*)d_in[10];
  const float* b2  = (const float*)d_in[11];
  const float* g1  = (const float*)d_in[12];
  const float* be1 = (const float*)d_in[13];
  const float* g2  = (const float*)d_in[14];
  const float* be2 = (const float*)d_in[15];
  const float* gf  = (const float*)d_in[16];
  const float* bef = (const float*)d_in[17];
  float* out = (float*)d_out;

  // allow 128 KB dynamic LDS (idempotent, host-side, capture-safe)
  (void)hipFuncSetAttribute((const void*)gemm256<0>, hipFuncAttributeMaxDynamicSharedMemorySize, 131072);
  (void)hipFuncSetAttribute((const void*)gemm256<2>, hipFuncAttributeMaxDynamicSharedMemorySize, 131072);
  (void)hipFuncSetAttribute((const void*)gemm256<3>, hipFuncAttributeMaxDynamicSharedMemorySize, 131072);

  char* p = (char*)d_ws;
  auto take = [&p](size_t bytes) { char* r = p; p += (bytes + 255) & ~(size_t)255; return r; };
  float* xf   = (float*)take((size_t)MROWS * EMB * 4);
  bf16*  hb   = (bf16*) take((size_t)MROWS * EMB * 2);
  bf16*  qkvb = (bf16*) take((size_t)MROWS * QKVSTR * 2);
  bf16*  vtb  = (bf16*) take((size_t)MROWS * EMB * 2);
  bf16*  ab   = (bf16*) take((size_t)MROWS * EMB * 2);
  bf16*  fb   = (bf16*) take((size_t)MROWS * FFND * 2);
  bf16*  tokT = (bf16*) take((size_t)VOCAB * EMB * 2);
  bf16*  wT   = (bf16*) take((size_t)WT_LAYER * 2);      // per-layer transposed pack

  k_f32_to_bf16<<<2048, 256, 0, stream>>>(tok, tokT, (long)VOCAB * EMB / 4);
  k_embed<<<MROWS, 256, 0, stream>>>(idx, tok, pos, xf);

  for (int l = 0; l < LAYERS; l++) {
    const size_t we = (size_t)l * EMB * EMB;
    const size_t wfo = (size_t)l * EMB * FFND;
    // fused: transpose layer-l weights + LN1 (13312 blocks)
    k_prep<<<12288 + MROWS / 4, 256, 0, stream>>>(
        wq + we, wk + we, wv + we, wo + we, w1 + wfo, w2 + wfo, wT,
        xf, g1 + l * EMB, be1 + l * EMB, hb);
    bf16* const qkvTl = wT + WT_QKV;
    bf16* const woTl  = wT + WT_WO;
    bf16* const w1Tl  = wT + WT_W1;
    bf16* const w2Tl  = wT + WT_W2;

    gemm256<0><<<dim3(QKVSTR / 256, MROWS / 256), 512, 131072, stream>>>(
        hb, qkvTl, MROWS, QKVSTR, EMB, qkvb, nullptr, vtb, nullptr);
    k_attn<<<dim3(SEQ / 128, NBATCH * HEADS), 256, 0, stream>>>(qkvb, vtb, ab);
    gemm_bt<<<dim3(EMB / BN, MROWS / BM, 2), 256, 0, stream>>>(ab, woTl, MROWS, EMB, EMB, xf, bo + l * EMB);
    k_layernorm<<<MROWS / 4, 256, 0, stream>>>(xf, g2 + l * EMB, be2 + l * EMB, hb);
    gemm256<2><<<dim3(FFND / 256, MROWS / 256), 512, 131072, stream>>>(
        hb, w1Tl, MROWS, FFND, EMB, fb, b1 + l * FFND, nullptr, nullptr);
    gemm_bt<<<dim3(EMB / BN, MROWS / BM, 2), 256, 0, stream>>>(fb, w2Tl, MROWS, EMB, FFND, xf, b2 + l * EMB);
  }

  k_layernorm<<<MROWS / 4, 256, 0, stream>>>(xf, gf, bef, hb);
  // logits: proven single-pipeline form; grid 125x16 = 2000 blocks (%8==0)
  gemm256<3><<<dim3(VOCAB / 256, MROWS / 256), 512, 131072, stream>>>(
      hb, tokT, MROWS, VOCAB, EMB, nullptr, nullptr, nullptr, out);
}

// Round 17
// 2510.565 us; speedup vs baseline: 1.0615x; 1.0051x over previous
//
#include <hip/hip_runtime.h>
#include <hip/hip_bf16.h>
#include <cstdint>
#include <cstddef>

#define LAYERS   8
#define HEADS    16
#define EMB      1024
#define FFND     4096
#define VOCAB    32000
#define SEQ      2048
#define NBATCH   2
#define MROWS    (NBATCH*SEQ)   // 4096
#define HDIM     64
#define QKVSTR   3072
#define LN_EPS   1e-5f
#define QSCALE   0.18033688011112042f   // (1/sqrt(64)) * log2(e)

// transposed-weight pack layout (elements)
#define WT_QKV   0
#define WT_WO    3145728
#define WT_W1    4194304
#define WT_W2    8388608
#define WT_LAYER 12582912

typedef __hip_bfloat16 bf16;
typedef short short8 __attribute__((ext_vector_type(8)));   // 8 x bf16 bits (4 VGPRs)
typedef float f32x4  __attribute__((ext_vector_type(4)));

// ---------------- async global->LDS (16B per lane) ----------------
__device__ __forceinline__ void async_copy16(const bf16* g, bf16* l) {
  __builtin_amdgcn_global_load_lds(
      (const __attribute__((address_space(1))) void*)g,
      (__attribute__((address_space(3))) void*)l, 16, 0, 0);
}

__device__ __forceinline__ uint32_t bfbits(float x) {
  __hip_bfloat16 h = __float2bfloat16(x);
  return (uint32_t)reinterpret_cast<uint16_t&>(h);
}

// ---------------- fused init: tok_emb->bf16 convert (bid<2048) + embedding ----------------
struct __align__(8) B4 { bf16 a, b, c, d; };

__global__ __launch_bounds__(256)
void k_init(const float* __restrict__ tok, bf16* __restrict__ tokT,
            const int* __restrict__ idx, const float* __restrict__ pos,
            float* __restrict__ x) {
  const int bid = blockIdx.x;
  if (bid < 2048) {
    // fp32 -> bf16 bulk convert of tok_emb (grid-stride over 2048 blocks)
    const long n4 = (long)VOCAB * EMB / 4;
    long i = (long)bid * blockDim.x + threadIdx.x;
    const long stride = 2048L * blockDim.x;
    for (; i < n4; i += stride) {
      float4 v = reinterpret_cast<const float4*>(tok)[i];
      B4 o;
      o.a = __float2bfloat16(v.x);
      o.b = __float2bfloat16(v.y);
      o.c = __float2bfloat16(v.z);
      o.d = __float2bfloat16(v.w);
      reinterpret_cast<B4*>(tokT)[i] = o;
    }
  } else {
    // x = tok_emb[idx] + pos_emb
    const int row  = bid - 2048;           // 0..4095 = b*SEQ + t
    const int tpos = row & (SEQ - 1);
    const int token = idx[row];
    const float4* te = (const float4*)(tok + (long)token * EMB);
    const float4* pe = (const float4*)(pos + (long)tpos * EMB);
    float4* xo = (float4*)(x + (long)row * EMB);
    for (int i = threadIdx.x; i < EMB / 4; i += blockDim.x) {
      float4 a = te[i], b = pe[i];
      a.x += b.x; a.y += b.y; a.z += b.z; a.w += b.w;
      xo[i] = a;
    }
  }
}

// ======================================================================
// Fused per-layer prep: weight transpose (blocks 0..12287) + LN1
// (blocks 12288..13311). Per-layer (NOT an 8-layer prepass): keeps
// transposed weights L3-hot (round-14 lesson: prepass cost ~90us).
// ======================================================================
__global__ __launch_bounds__(256)
void k_prep(const float* __restrict__ wq, const float* __restrict__ wk,
            const float* __restrict__ wv, const float* __restrict__ wo,
            const float* __restrict__ w1, const float* __restrict__ w2,
            bf16* __restrict__ wT,
            const float* __restrict__ x, const float* __restrict__ g,
            const float* __restrict__ b, bf16* __restrict__ outLN) {
  const int bid = blockIdx.x;
  if (bid < 12288) {
    // ---- weight transpose: fp32 [K][N] -> bf16 [N][K] ----
    __shared__ float tile[32][33];
    const float* in; bf16* out; int K, N, bx, by;
    if (bid < 4096) {
      const int rest = bid & 1023;
      switch (bid >> 10) {
        case 0:  in = wq; out = wT + WT_QKV;               break;
        case 1:  in = wk; out = wT + WT_QKV + EMB * EMB;   break;
        case 2:  in = wv; out = wT + WT_QKV + 2 * EMB * EMB; break;
        default: in = wo; out = wT + WT_WO;                break;
      }
      K = EMB; N = EMB; bx = rest & 31; by = rest >> 5;
    } else if (bid < 8192) {
      const int rest = bid - 4096;
      in = w1; out = wT + WT_W1; K = EMB; N = FFND;
      bx = rest & 127; by = rest >> 7;
    } else {
      const int rest = bid - 8192;
      in = w2; out = wT + WT_W2; K = FFND; N = EMB;
      bx = rest & 31; by = rest >> 5;
    }
    const int n0 = bx * 32, k0 = by * 32;
    const int tx = threadIdx.x & 31, ty = threadIdx.x >> 5;   // (32,8)
    for (int i = 0; i < 32; i += 8)
      tile[ty + i][tx] = in[(long)(k0 + ty + i) * N + n0 + tx];
    __syncthreads();
    for (int i = 0; i < 32; i += 8)
      out[(long)(n0 + ty + i) * K + k0 + tx] = __float2bfloat16(tile[tx][ty + i]);
  } else {
    // ---- LayerNorm: wave-per-row (4 rows/block), fp32 in -> bf16 out ----
    const int wid  = threadIdx.x >> 6;
    const int lane = threadIdx.x & 63;
    const long row = (long)(bid - 12288) * 4 + wid;
    const float4* xr = (const float4*)(x + row * EMB);
    float4 xv[4];
    float s = 0.f, sq = 0.f;
#pragma unroll
    for (int i = 0; i < 4; i++) {
      xv[i] = xr[lane + i * 64];
      s  += xv[i].x + xv[i].y + xv[i].z + xv[i].w;
      sq += xv[i].x * xv[i].x + xv[i].y * xv[i].y + xv[i].z * xv[i].z + xv[i].w * xv[i].w;
    }
#pragma unroll
    for (int m = 1; m < 64; m <<= 1) { s += __shfl_xor(s, m); sq += __shfl_xor(sq, m); }
    const float mean = s * (1.f / EMB);
    const float var  = sq * (1.f / EMB) - mean * mean;
    const float rstd = rsqrtf(var + LN_EPS);
    const float4* gv = (const float4*)g;
    const float4* bv = (const float4*)b;
    bf16* orow = outLN + row * EMB;
#pragma unroll
    for (int i = 0; i < 4; i++) {
      const int c4 = lane + i * 64;
      const float4 gg = gv[c4], bb = bv[c4];
      uint2 o;
      o.x = (bfbits((xv[i].y - mean) * rstd * gg.y + bb.y) << 16) |
             bfbits((xv[i].x - mean) * rstd * gg.x + bb.x);
      o.y = (bfbits((xv[i].w - mean) * rstd * gg.w + bb.w) << 16) |
             bfbits((xv[i].z - mean) * rstd * gg.z + bb.z);
      *reinterpret_cast<uint2*>(&orow[c4 * 4]) = o;
    }
  }
}

// ---------------- LayerNorm: wave-per-row (4 rows/block), fp32 in -> bf16 out ----------------
__global__ __launch_bounds__(256)
void k_layernorm(const float* __restrict__ x, const float* __restrict__ g,
                 const float* __restrict__ b, bf16* __restrict__ out) {
  const int wid  = threadIdx.x >> 6;
  const int lane = threadIdx.x & 63;
  const long row = (long)blockIdx.x * 4 + wid;
  const float4* xr = (const float4*)(x + row * EMB);
  float4 xv[4];
  float s = 0.f, sq = 0.f;
#pragma unroll
  for (int i = 0; i < 4; i++) {
    xv[i] = xr[lane + i * 64];
    s  += xv[i].x + xv[i].y + xv[i].z + xv[i].w;
    sq += xv[i].x * xv[i].x + xv[i].y * xv[i].y + xv[i].z * xv[i].z + xv[i].w * xv[i].w;
  }
#pragma unroll
  for (int m = 1; m < 64; m <<= 1) { s += __shfl_xor(s, m); sq += __shfl_xor(sq, m); }
  const float mean = s * (1.f / EMB);
  const float var  = sq * (1.f / EMB) - mean * mean;
  const float rstd = rsqrtf(var + LN_EPS);
  const float4* gv = (const float4*)g;
  const float4* bv = (const float4*)b;
  bf16* orow = out + row * EMB;
#pragma unroll
  for (int i = 0; i < 4; i++) {
    const int c4 = lane + i * 64;
    const float4 gg = gv[c4], bb = bv[c4];
    uint2 o;
    o.x = (bfbits((xv[i].y - mean) * rstd * gg.y + bb.y) << 16) |
           bfbits((xv[i].x - mean) * rstd * gg.x + bb.x);
    o.y = (bfbits((xv[i].w - mean) * rstd * gg.w + bb.w) << 16) |
           bfbits((xv[i].z - mean) * rstd * gg.z + bb.z);
    *reinterpret_cast<uint2*>(&orow[c4 * 4]) = o;
  }
}

// ======================================================================
// 256x256 GEMM, 2 super-phases/tile. C[M,N] = A[M,K]*Bt[N,K]^T
// MODE 0 (QKV): Q cols (<EMB) pre-scaled by QSCALE -> outB; K cols -> outB;
//   V cols (>=2*EMB) written TRANSPOSED into vt_out[bh*64+d][t].
// MODE 2: outB = bf16(relu(acc+bias)); MODE 3: outF = acc (fp32, single
// epilogue at kernel end -- stores must never interleave the vmcnt ring).
// ======================================================================
template<int MODE>
__global__ __launch_bounds__(512, 2)
void gemm256(const bf16* __restrict__ A, const bf16* __restrict__ Bt,
             int M, int N, int K,
             bf16* __restrict__ outB, const float* __restrict__ bias,
             bf16* __restrict__ vt_out, float* __restrict__ outF) {
  extern __shared__ __align__(16) char smem[];   // 128 KB
  char* const smA = smem;
  char* const smB = smem + 65536;

  const int t    = threadIdx.x;
  const int lane = t & 63;
  const int wid  = t >> 6;
  const int wr   = wid >> 2;          // 0..1 : A half (rows wr*128..)
  const int wc   = wid & 3;           // 0..3 : cols wc*64.. ; B half = wc>>1
  const int lrow = lane & 15;
  const int ks16 = (lane >> 4) * 16;  // k-slice byte offset
  const int rswz = (lrow & 7) << 4;   // read-side XOR

  // linearize + bijective XCD chunk swizzle (nwg % 8 == 0)
  int lin = blockIdx.x * gridDim.y + blockIdx.y;
  { const int nwg = gridDim.x * gridDim.y; const int per = nwg >> 3;
    lin = (lin & 7) * per + (lin >> 3); }
  const int gx8  = gridDim.x * 8;
  const int half = lin / gx8;
  const int rem  = lin - half * gx8;
  const long bm  = (long)(half * 8 + (rem & 7)) * 256;
  const long bn  = (long)(rem >> 3) * 256;
  const int NT = K >> 6;

  const int row0 = wid * 8 + (lane >> 3);               // dest row of load 0
  const int col0 = ((lane & 7) ^ (lane >> 3)) * 8;      // pre-swizzled src col
  const int row1 = row0 + 64;                           // load 1: row+64, same col
  const int dst0 = wid * 1024;
  const int dst1 = 8192 + wid * 1024;
  const bf16* const gA = A + bm * K;
  const bf16* const gB = Bt + bn * K;

  auto STG = [&](char* ring, const bf16* g_, int tile, int h) {
    char* slot = ring + (((tile << 1) + h) & 3) * 16384;
    const bf16* sb = g_ + ((long)h * 128) * K + (long)tile * 64;
    async_copy16(sb + (long)row0 * K + col0, (bf16*)(slot + dst0));
    async_copy16(sb + (long)row1 * K + col0, (bf16*)(slot + dst1));
  };
  auto LDA8 = [&](int u, int m, int kk) -> short8 {
    const int off = (m * 16 + lrow) * 128 + ((kk * 64 + ks16) ^ rswz);
    return *reinterpret_cast<const short8*>(smA + (((u << 1) + wr) & 3) * 16384 + off);
  };
  auto LDB8 = [&](int u, int n, int kk) -> short8 {
    const int off = ((wc & 1) * 64 + n * 16 + lrow) * 128 + ((kk * 64 + ks16) ^ rswz);
    return *reinterpret_cast<const short8*>(smB + (((u << 1) + (wc >> 1)) & 3) * 16384 + off);
  };
#define MF(a_, b_, c_) __builtin_amdgcn_mfma_f32_16x16x32_bf16(a_, b_, c_, 0, 0, 0)

  f32x4 acc[8][4] = {};

  // prologue: B(0) A(0) B(1); last 4 loads (B(1)) may stay in flight
  STG(smB, gB, 0, 0); STG(smB, gB, 0, 1);
  STG(smA, gA, 0, 0); STG(smA, gA, 0, 1);
  STG(smB, gB, 1, 0); STG(smB, gB, 1, 1);
  asm volatile("s_waitcnt vmcnt(4)" ::: "memory");
  __builtin_amdgcn_s_barrier();

  short8 bq[4][2];
  for (int u = 0; u < NT; u++) {
    // ---- super-phase A: read B(all) + A(m0..m3); stage A(u+1) ----
#pragma unroll
    for (int n = 0; n < 4; n++) { bq[n][0] = LDB8(u, n, 0); bq[n][1] = LDB8(u, n, 1); }
    short8 a0 = LDA8(u, 0, 0), a1 = LDA8(u, 0, 1), a2 = LDA8(u, 1, 0), a3 = LDA8(u, 1, 1);
    short8 a4 = LDA8(u, 2, 0), a5 = LDA8(u, 2, 1), a6 = LDA8(u, 3, 0), a7 = LDA8(u, 3, 1);
    if (u + 1 < NT) { STG(smA, gA, u + 1, 0); STG(smA, gA, u + 1, 1); }
    __builtin_amdgcn_s_barrier();
    asm volatile("s_waitcnt lgkmcnt(0)" ::: "memory");
    __builtin_amdgcn_sched_barrier(0);
    __builtin_amdgcn_s_setprio(1);
#pragma unroll
    for (int n = 0; n < 4; n++) {
      acc[0][n] = MF(a0, bq[n][0], acc[0][n]); acc[0][n] = MF(a1, bq[n][1], acc[0][n]);
      acc[1][n] = MF(a2, bq[n][0], acc[1][n]); acc[1][n] = MF(a3, bq[n][1], acc[1][n]);
      acc[2][n] = MF(a4, bq[n][0], acc[2][n]); acc[2][n] = MF(a5, bq[n][1], acc[2][n]);
      acc[3][n] = MF(a6, bq[n][0], acc[3][n]); acc[3][n] = MF(a7, bq[n][1], acc[3][n]);
    }
    __builtin_amdgcn_s_setprio(0);
    __builtin_amdgcn_s_barrier();

    // ---- super-phase B: read A(m4..m7); stage B(u+2); tile-end wait ----
    a0 = LDA8(u, 4, 0); a1 = LDA8(u, 4, 1); a2 = LDA8(u, 5, 0); a3 = LDA8(u, 5, 1);
    a4 = LDA8(u, 6, 0); a5 = LDA8(u, 6, 1); a6 = LDA8(u, 7, 0); a7 = LDA8(u, 7, 1);
    if (u + 2 < NT) { STG(smB, gB, u + 2, 0); STG(smB, gB, u + 2, 1); }
    __builtin_amdgcn_s_barrier();
    asm volatile("s_waitcnt lgkmcnt(0)" ::: "memory");
    __builtin_amdgcn_sched_barrier(0);
    __builtin_amdgcn_s_setprio(1);
#pragma unroll
    for (int n = 0; n < 4; n++) {
      acc[4][n] = MF(a0, bq[n][0], acc[4][n]); acc[4][n] = MF(a1, bq[n][1], acc[4][n]);
      acc[5][n] = MF(a2, bq[n][0], acc[5][n]); acc[5][n] = MF(a3, bq[n][1], acc[5][n]);
      acc[6][n] = MF(a4, bq[n][0], acc[6][n]); acc[6][n] = MF(a5, bq[n][1], acc[6][n]);
      acc[7][n] = MF(a6, bq[n][0], acc[7][n]); acc[7][n] = MF(a7, bq[n][1], acc[7][n]);
    }
    __builtin_amdgcn_s_setprio(0);
    if (u + 2 < NT) { asm volatile("s_waitcnt vmcnt(4)" ::: "memory"); }
    else            { asm volatile("s_waitcnt vmcnt(0)" ::: "memory"); }
    __builtin_amdgcn_s_barrier();
  }

  // epilogue (single, at kernel end)
  const long rb = bm + wr * 128 + (lane >> 4) * 4;
  const long cb = bn + wc * 64 + lrow;
#pragma unroll
  for (int m = 0; m < 8; m++) {
#pragma unroll
    for (int n = 0; n < 4; n++) {
      const long col = cb + n * 16;
      if (MODE == 0 && col >= 2 * EMB) {
        // V slice: write transposed into vt_out[(b*16+h)*64+d][t], 4 consecutive t
        const int  dc = (int)(col - 2 * EMB);
        const long t0 = rb + m * 16;
        const long vr = ((t0 >> 11) * HEADS + (dc >> 6)) * (long)HDIM + (dc & 63);
        uint2 pv;
        pv.x = (bfbits(acc[m][n][1]) << 16) | bfbits(acc[m][n][0]);
        pv.y = (bfbits(acc[m][n][3]) << 16) | bfbits(acc[m][n][2]);
        *reinterpret_cast<uint2*>(&vt_out[vr * SEQ + (t0 & (SEQ - 1))]) = pv;
      } else {
#pragma unroll
        for (int r = 0; r < 4; r++) {
          const long row = rb + m * 16 + r;
          float vv = acc[m][n][r];
          if (MODE == 0) {
            if (col < EMB) vv *= QSCALE;     // pre-scale Q slice for attention
            outB[row * N + col] = __float2bfloat16(vv);
          } else if (MODE == 2) {
            vv += bias[col];
            outB[row * N + col] = __float2bfloat16(vv > 0.f ? vv : 0.f);
          } else {
            outF[row * N + col] = vv;
          }
        }
      }
    }
  }
#undef MF
}

// ---------------- 128x128 GEMM, split-K=2 + 2-phase dbuf ----------------
#define BM 128
#define BN 128
#define BK 32

__global__ __launch_bounds__(256)
void gemm_bt(const bf16* __restrict__ A, const bf16* __restrict__ Bt,
             int M, int N, int K,
             float* __restrict__ outF, const float* __restrict__ bias) {
  __shared__ __align__(16) bf16 lA[2][BM * BK];
  __shared__ __align__(16) bf16 lB[2][BN * BK];
  const int t    = threadIdx.x;
  const int lane = t & 63;
  const int wid  = t >> 6;
  const int wr   = wid >> 1;
  const int wc   = wid & 1;
  const long bm  = (long)blockIdx.y * BM;
  const long bn  = (long)blockIdx.x * BN;
  const int  kz  = blockIdx.z;
  const int  Kh  = K >> 1;

  f32x4 acc[4][4] = {};

  const long arow = t >> 2;                               // 0..63
  const int  acol = (((t & 3) ^ ((t >> 2) & 3)) * 8);     // pre-swizzled src col
  const bf16* gA = A  + (bm + arow) * K + kz * Kh + acol;
  const bf16* gB = Bt + (bn + arow) * K + kz * Kh + acol;
  const long astep = 64L * K;

  auto STGBT = [&](int buf, int k0) {
    async_copy16(gA + k0,         &lA[buf][wid * 512]);
    async_copy16(gA + k0 + astep, &lA[buf][wid * 512 + 2048]);
    async_copy16(gB + k0,         &lB[buf][wid * 512]);
    async_copy16(gB + k0 + astep, &lB[buf][wid * 512 + 2048]);
  };

  STGBT(0, 0);
  __syncthreads();

  int cur = 0;
  for (int k0 = 0; k0 < Kh; k0 += BK) {
    if (k0 + BK < Kh) STGBT(cur ^ 1, k0 + BK);   // overlaps with compute below

    const int ksel = (((lane >> 4) ^ (lane & 3)) * 8);    // swizzled read col
    short8 af[4], bfv[4];
#pragma unroll
    for (int i = 0; i < 4; i++) {
      af[i]  = *reinterpret_cast<const short8*>(&lA[cur][(wr * 64 + i * 16 + (lane & 15)) * BK + ksel]);
      bfv[i] = *reinterpret_cast<const short8*>(&lB[cur][(wc * 64 + i * 16 + (lane & 15)) * BK + ksel]);
    }
#pragma unroll
    for (int i = 0; i < 4; i++)
#pragma unroll
      for (int j = 0; j < 4; j++)
        acc[i][j] = __builtin_amdgcn_mfma_f32_16x16x32_bf16(af[i], bfv[j], acc[i][j], 0, 0, 0);
    __syncthreads();   // drains next-tile stage; protects cur buffer reuse
    cur ^= 1;
  }

  const long rbase = bm + wr * 64 + (lane >> 4) * 4;
  const long cbase = bn + wc * 64 + (lane & 15);
#pragma unroll
  for (int i = 0; i < 4; i++) {
#pragma unroll
    for (int j = 0; j < 4; j++) {
      const long col = cbase + j * 16;
      const float bv = kz ? 0.f : bias[col];
#pragma unroll
      for (int r = 0; r < 4; r++) {
        const long row = rbase + i * 16 + r;
        unsafeAtomicAdd(&outF[row * N + col], acc[i][j][r] + bv);
      }
    }
  }
}

// ---------------- flash attention (causal), 2 q-frags/wave, defer-max, paired balance ----------------
// Round-17: T5 s_setprio around MFMA clusters (m191 regime: independent
// blocks per CU at different k-tile phases -> scheduler favors MFMA waves).
__global__ __launch_bounds__(256)
void k_attn(const bf16* __restrict__ qkv, const bf16* __restrict__ vt, bf16* __restrict__ o) {
  const int bh = blockIdx.y;
  const int qt = (bh & 16) ? blockIdx.x : (gridDim.x - 1 - blockIdx.x);
  const int b  = bh >> 4;
  const int h  = bh & 15;
  const int t0b = qt * 128;
  const int tid = threadIdx.x;
  const int w    = tid >> 6;
  const int lane = tid & 63;
  const int lg = lane >> 4;            // 0..3
  const int li = lane & 15;
  const int t0w = t0b + w * 32;        // frag f rows: t0w + f*16 + li

  __shared__ __align__(16) bf16 Kl[2][64 * 64];
  __shared__ __align__(16) bf16 Vl[2][64 * 64];
  __shared__ __align__(16) bf16 Pl[4][32 * 64];   // per-wave P[q][k], swizzled

  const bf16* qbase = qkv + (long)(b * SEQ) * QKVSTR + h * HDIM;   // Q pre-scaled by QSCALE
  const bf16* kbase = qkv + (long)(b * SEQ) * QKVSTR + EMB + h * HDIM;
  const bf16* vbase = vt + (long)bh * HDIM * SEQ;

  short8 qf[2][2];
#pragma unroll
  for (int f = 0; f < 2; f++) {
    const bf16* qrow = qbase + (long)(t0w + f * 16 + li) * QKVSTR;
    qf[f][0] = *reinterpret_cast<const short8*>(&qrow[lg * 8]);
    qf[f][1] = *reinterpret_cast<const short8*>(&qrow[32 + lg * 8]);
  }

  f32x4 oacc[2][4] = {};
  float mrow[2] = {-1e30f, -1e30f}, lrow[2] = {0.f, 0.f};

  const int nkt = (t0b >> 6) + 1;            // last k-tile index (diag spans 2 tiles)
  const int l8  = lane >> 3;                 // 0..7
  const int sl8 = ((lane & 7) ^ l8) * 8;     // pre-swizzled source slot (rule 21)

  char* const Pw = (char*)&Pl[w][0];
  const int pswz = (li & 7) << 4;

  // prologue: stage tile 0 into buffer 0
#pragma unroll
  for (int sh = 0; sh < 2; sh++) {
    const int r = sh * 32 + w * 8 + l8;
    async_copy16(kbase + (long)r * QKVSTR + sl8, &Kl[0][(sh * 32 + w * 8) * 64]);
    async_copy16(vbase + (long)r * SEQ + sl8,    &Vl[0][(sh * 32 + w * 8) * 64]);
  }
  __syncthreads();

  int cur = 0;
  for (int kt = 0; kt <= nkt; kt++) {
    const int s0 = kt * 64;
    if (kt < nkt) {                          // stage next tile
      const int s0n = s0 + 64;
      bf16* Kn = &Kl[cur ^ 1][0];
      bf16* Vn = &Vl[cur ^ 1][0];
#pragma unroll
      for (int sh = 0; sh < 2; sh++) {
        const int r = sh * 32 + w * 8 + l8;
        async_copy16(kbase + (long)(s0n + r) * QKVSTR + sl8, Kn + (sh * 32 + w * 8) * 64);
        async_copy16(vbase + (long)r * SEQ + s0n + sl8,      Vn + (sh * 32 + w * 8) * 64);
      }
    }

    // S^T = mfma(K, Q) — Q already carries QSCALE (exp2 domain)
    f32x4 s[2][4] = {};
    __builtin_amdgcn_s_setprio(1);
#pragma unroll
    for (int kk = 0; kk < 2; kk++)
#pragma unroll
      for (int sf = 0; sf < 4; sf++) {
        const short8 kf = *reinterpret_cast<const short8*>(
            &Kl[cur][(sf * 16 + li) * 64 + ((((kk << 2) | lg) ^ (li & 7)) * 8)]);
        s[0][sf] = __builtin_amdgcn_mfma_f32_16x16x32_bf16(kf, qf[0][kk], s[0][sf], 0, 0, 0);
        s[1][sf] = __builtin_amdgcn_mfma_f32_16x16x32_bf16(kf, qf[1][kk], s[1][sf], 0, 0, 0);
      }
    __builtin_amdgcn_s_setprio(0);

    const bool diag = (kt >= nkt - 1);       // tiles < nkt-1 provably unmasked
    if (diag) {
#pragma unroll
      for (int f = 0; f < 2; f++)
#pragma unroll
        for (int sf = 0; sf < 4; sf++)
#pragma unroll
          for (int r = 0; r < 4; r++)
            if (s0 + sf * 16 + lg * 4 + r > t0w + f * 16 + li) s[f][sf][r] = -1e30f;
    }

    // per-lane softmax per frag, defer-max (T13, THR=8 in exp2 domain)
#pragma unroll
    for (int f = 0; f < 2; f++) {
      float mx = -1e30f;
#pragma unroll
      for (int sf = 0; sf < 4; sf++)
        mx = fmaxf(mx, fmaxf(fmaxf(s[f][sf][0], s[f][sf][1]), fmaxf(s[f][sf][2], s[f][sf][3])));
      mx = fmaxf(mx, __shfl_xor(mx, 16));
      mx = fmaxf(mx, __shfl_xor(mx, 32));
      if (__any(mx > mrow[f] + 8.f)) {       // rescale only when max grew materially
        const float mnew = fmaxf(mrow[f], mx);
        const float alpha = exp2f(mrow[f] - mnew);
        mrow[f] = mnew;
        lrow[f] *= alpha;
#pragma unroll
        for (int d = 0; d < 4; d++)
#pragma unroll
          for (int r = 0; r < 4; r++) oacc[f][d][r] *= alpha;
      }
      float rs = 0.f;
#pragma unroll
      for (int sf = 0; sf < 4; sf++)
#pragma unroll
        for (int r = 0; r < 4; r++) {
          const float pv = exp2f(s[f][sf][r] - mrow[f]);   // bounded by 2^8
          s[f][sf][r] = pv;
          rs += pv;
        }
      rs += __shfl_xor(rs, 16);
      rs += __shfl_xor(rs, 32);
      lrow[f] += rs;

      // P write: row f*16+li, 4 contiguous k per sf, 16B-granule swizzle
#pragma unroll
      for (int sf = 0; sf < 4; sf++) {
        uint2 pw2;
        pw2.x = (bfbits(s[f][sf][1]) << 16) | bfbits(s[f][sf][0]);
        pw2.y = (bfbits(s[f][sf][3]) << 16) | bfbits(s[f][sf][2]);
        *reinterpret_cast<uint2*>(Pw + (f * 16 + li) * 128 + ((sf * 32 + lg * 8) ^ pswz)) = pw2;
      }
    }

    // O^T += mfma(V, P^T); vf shared across frags
    __builtin_amdgcn_s_setprio(1);
#pragma unroll
    for (int kk = 0; kk < 2; kk++) {
      const short8 pb0 = *reinterpret_cast<const short8*>(
          Pw + li * 128 + ((kk * 64 + lg * 16) ^ pswz));
      const short8 pb1 = *reinterpret_cast<const short8*>(
          Pw + (16 + li) * 128 + ((kk * 64 + lg * 16) ^ pswz));
#pragma unroll
      for (int d = 0; d < 4; d++) {
        const short8 vf = *reinterpret_cast<const short8*>(
            &Vl[cur][(d * 16 + li) * 64 + ((((kk << 2) | lg) ^ (li & 7)) * 8)]);
        oacc[0][d] = __builtin_amdgcn_mfma_f32_16x16x32_bf16(vf, pb0, oacc[0][d], 0, 0, 0);
        oacc[1][d] = __builtin_amdgcn_mfma_f32_16x16x32_bf16(vf, pb1, oacc[1][d], 0, 0, 0);
      }
    }
    __builtin_amdgcn_s_setprio(0);

    if (kt < nkt) {                // final iteration: nothing staged, no reuse
      __syncthreads();             // drains stage vmcnt + protects buf reuse
      cur ^= 1;
    }
  }

  // epilogue: lane owns rows q = t0w + f*16 + li
#pragma unroll
  for (int f = 0; f < 2; f++) {
    const float inv = 1.f / lrow[f];
    bf16* orow = o + (long)(b * SEQ + t0w + f * 16 + li) * EMB + h * HDIM;
#pragma unroll
    for (int d = 0; d < 4; d++) {
      uint2 ow;
      ow.x = (bfbits(oacc[f][d][1] * inv) << 16) | bfbits(oacc[f][d][0] * inv);
      ow.y = (bfbits(oacc[f][d][3] * inv) << 16) | bfbits(oacc[f][d][2] * inv);
      *reinterpret_cast<uint2*>(&orow[d * 16 + lg * 4]) = ow;
    }
  }
}

// ---------------- host launcher ----------------
extern "C" void kernel_launch(void* const* d_in, const int* in_sizes, int n_in,
                              void* d_out, int out_size, void* d_ws, size_t ws_size,
                              hipStream_t stream) {
  (void)in_sizes; (void)n_in; (void)out_size; (void)ws_size;
  const int*   idx = (const int*)  d_in[0];
  const float* tok = (const float*)d_in[1];
  const float* pos = (const float*)d_in[2];
  const float* wq  = (const float*)d_in[3];
  const float* wk  = (const float*)d_in[4];
  const float* wv  = (const float*)d_in[5];
  const float* wo  = (const float*)d_in[6];
  const float* bo  = (const float*)d_in[7];
  const float* w1  = (const float*)d_in[8];
  const float* b1  = (const float*)d_in[9];
  const float* w2  = (const float*)d_in[10];
  const float* b2  = (const float*)d_in[11];
  const float* g1  = (const float*)d_in[12];
  const float* be1 = (const float*)d_in[13];
  const float* g2  = (const float*)d_in[14];
  const float* be2 = (const float*)d_in[15];
  const float* gf  = (const float*)d_in[16];
  const float* bef = (const float*)d_in[17];
  float* out = (float*)d_out;

  // allow 128 KB dynamic LDS (idempotent, host-side, capture-safe)
  (void)hipFuncSetAttribute((const void*)gemm256<0>, hipFuncAttributeMaxDynamicSharedMemorySize, 131072);
  (void)hipFuncSetAttribute((const void*)gemm256<2>, hipFuncAttributeMaxDynamicSharedMemorySize, 131072);
  (void)hipFuncSetAttribute((const void*)gemm256<3>, hipFuncAttributeMaxDynamicSharedMemorySize, 131072);

  char* p = (char*)d_ws;
  auto take = [&p](size_t bytes) { char* r = p; p += (bytes + 255) & ~(size_t)255; return r; };
  float* xf   = (float*)take((size_t)MROWS * EMB * 4);
  bf16*  hb   = (bf16*) take((size_t)MROWS * EMB * 2);
  bf16*  qkvb = (bf16*) take((size_t)MROWS * QKVSTR * 2);
  bf16*  vtb  = (bf16*) take((size_t)MROWS * EMB * 2);
  bf16*  ab   = (bf16*) take((size_t)MROWS * EMB * 2);
  bf16*  fb   = (bf16*) take((size_t)MROWS * FFND * 2);
  bf16*  tokT = (bf16*) take((size_t)VOCAB * EMB * 2);
  bf16*  wT   = (bf16*) take((size_t)WT_LAYER * 2);      // per-layer transposed pack

  // fused: tok_emb convert + embedding (2048 + 4096 blocks)
  k_init<<<2048 + MROWS, 256, 0, stream>>>(tok, tokT, idx, pos, xf);

  for (int l = 0; l < LAYERS; l++) {
    const size_t we = (size_t)l * EMB * EMB;
    const size_t wfo = (size_t)l * EMB * FFND;
    // fused: transpose layer-l weights + LN1 (13312 blocks)
    k_prep<<<12288 + MROWS / 4, 256, 0, stream>>>(
        wq + we, wk + we, wv + we, wo + we, w1 + wfo, w2 + wfo, wT,
        xf, g1 + l * EMB, be1 + l * EMB, hb);
    bf16* const qkvTl = wT + WT_QKV;
    bf16* const woTl  = wT + WT_WO;
    bf16* const w1Tl  = wT + WT_W1;
    bf16* const w2Tl  = wT + WT_W2;

    gemm256<0><<<dim3(QKVSTR / 256, MROWS / 256), 512, 131072, stream>>>(
        hb, qkvTl, MROWS, QKVSTR, EMB, qkvb, nullptr, vtb, nullptr);
    k_attn<<<dim3(SEQ / 128, NBATCH * HEADS), 256, 0, stream>>>(qkvb, vtb, ab);
    gemm_bt<<<dim3(EMB / BN, MROWS / BM, 2), 256, 0, stream>>>(ab, woTl, MROWS, EMB, EMB, xf, bo + l * EMB);
    k_layernorm<<<MROWS / 4, 256, 0, stream>>>(xf, g2 + l * EMB, be2 + l * EMB, hb);
    gemm256<2><<<dim3(FFND / 256, MROWS / 256), 512, 131072, stream>>>(
        hb, w1Tl, MROWS, FFND, EMB, fb, b1 + l * FFND, nullptr, nullptr);
    gemm_bt<<<dim3(EMB / BN, MROWS / BM, 2), 256, 0, stream>>>(fb, w2Tl, MROWS, EMB, FFND, xf, b2 + l * EMB);
  }

  k_layernorm<<<MROWS / 4, 256, 0, stream>>>(xf, gf, bef, hb);
  // logits: proven single-pipeline form; grid 125x16 = 2000 blocks (%8==0)
  gemm256<3><<<dim3(VOCAB / 256, MROWS / 256), 512, 131072, stream>>>(
      hb, tokT, MROWS, VOCAB, EMB, nullptr, nullptr, nullptr, out);
}